// Round 9
// baseline (1327.631 us; speedup 1.0000x reference)
//
#include <hip/hip_runtime.h>
#include <stdint.h>

#define BB 32
#define TT 64
#define ID 300
#define HH 168
#define SS 512
#define VV 50257
#define G4 672     // 4*H
#define IC 468     // I + C
#define KP 192     // K padded (8 regions x 24, k-permuted)
#define NP2 50432  // V padded to 256 (197 tiles)
#define NJ 8       // blocks (j-slices) per batch
#define RPB 21     // h rows per j-slice
#define CPB 84     // gate cols per j-slice
#define KK 336     // gate K dim
#define WKP 88     // WgT col pad
#define SBLK 64    // s positions per j-slice
#define LSLOT 192  // u64 slots per (b,j) bucket
#define HROW 96    // u32 per hall row (KP/2)
#define LP 72      // decode LDS row pad in shorts
#define NTN 197    // decode n-tiles (50432/256)
#define EP 192     // padded ETs row (8 groups x 24 shorts)

typedef float f32x4 __attribute__((ext_vector_type(4)));
typedef short bf16x8 __attribute__((ext_vector_type(8)));
typedef unsigned long long u64;

__device__ __forceinline__ float bf2f(unsigned short u) {
  union { unsigned int i; float f; } v; v.i = ((unsigned int)u) << 16; return v.f;
}
__device__ __forceinline__ unsigned short f2bf(float f) {
  union { float f; unsigned int u; } v; v.f = f;
  unsigned int r = v.u + 0x7fffu + ((v.u >> 16) & 1u);
  return (unsigned short)(r >> 16);
}
__device__ __forceinline__ float rcpf(float x) { return __builtin_amdgcn_rcpf(x); }
__device__ __forceinline__ u64 packft(float f, unsigned tag) {
  union { float f; unsigned u; } v; v.f = f;
  return ((u64)tag << 32) | (u64)v.u;
}
__device__ __forceinline__ float lo_f(u64 x) {
  union { unsigned u; float f; } v; v.u = (unsigned)x; return v.f;
}
__device__ __forceinline__ unsigned hi_u(u64 x) { return (unsigned)(x >> 32); }
__device__ __forceinline__ void postv(u64* p, u64 v) {
  __hip_atomic_store(p, v, __ATOMIC_RELAXED, __HIP_MEMORY_SCOPE_AGENT);
}
__device__ __forceinline__ u64 loadv(const u64* p) {
  return __hip_atomic_load(p, __ATOMIC_RELAXED, __HIP_MEMORY_SCOPE_AGENT);
}
__device__ __forceinline__ void postu(unsigned* p, unsigned v) {
  __hip_atomic_store(p, v, __ATOMIC_RELAXED, __HIP_MEMORY_SCOPE_AGENT);
}

// ============ prep-all: Wdb (k-permuted), WihxT, WgT/WxS, zero Abuf/Pbuf =====
#define NB_WDEC 4728   // NP2*KP/8/256
#define NB_TR   788    // ceil(ID*G4/256)
__global__ void k_prepall(const float* __restrict__ Wih, const float* __restrict__ Whh,
                          const float* __restrict__ attWx, const float* __restrict__ Wd,
                          float* __restrict__ WihxT, unsigned short* __restrict__ Wdb,
                          float* __restrict__ WgT, unsigned short* __restrict__ WxS,
                          u64* __restrict__ Abuf, u64* __restrict__ Pbuf) {
  const int bid = blockIdx.x, tid = threadIdx.x;
  if (bid < NB_WDEC) {
    size_t e0 = ((size_t)bid * 256 + tid) * 8;
    int v = (int)(e0 / KP), kp0 = (int)(e0 - (size_t)v * KP);
    int rg = kp0 / 24, off0 = kp0 - rg * 24;   // off0 in {0,8,16}
    unsigned short o[8];
    if (v < VV) {
      const float* src = Wd + (size_t)v * HH + rg * RPB + off0;
      #pragma unroll
      for (int i = 0; i < 8; ++i) o[i] = (off0 + i < RPB) ? f2bf(src[i]) : 0;
    } else {
      #pragma unroll
      for (int i = 0; i < 8; ++i) o[i] = 0;
    }
    *(uint4*)(Wdb + e0) = *(const uint4*)o;
    return;
  }
  if (bid < NB_WDEC + NB_TR) {
    int idx = (bid - NB_WDEC) * 256 + tid;
    if (idx < ID * G4) {
      int k = idx / G4, i = idx - k * G4;
      WihxT[idx] = Wih[(size_t)i * IC + k];
    }
    return;
  }
  int idx = (bid - NB_WDEC - NB_TR) * 256 + tid;
  const int T1 = NJ * KK * WKP;             // 236544
  const int T2 = T1 + NJ * RPB * HH;        // +28224
  const int ZH = BB * NJ * LSLOT;           // 49152 u64 each
  const int T3 = T2 + 2 * ZH;
  if (idx < T1) {
    int j = idx / (KK * WKP); int r = idx - j * (KK * WKP);
    int k = r / WKP, col = r - k * WKP;
    float w = 0.f;
    if (col < CPB) {
      int gt = col / RPB, rr = col - gt * RPB;
      int gcol = gt * HH + j * RPB + rr;
      w = (k < HH) ? Wih[(size_t)gcol * IC + ID + k] : Whh[(size_t)gcol * HH + (k - HH)];
    }
    WgT[idx] = w;
  } else if (idx < T2) {
    int r = idx - T1;
    WxS[r] = f2bf(attWx[r]);
  } else if (idx < T3) {
    int r = idx - T2;
    if (r < ZH) Abuf[r] = 0ull;
    else        Pbuf[r - ZH] = 0ull;
  }
}

// ============ seqproj (blocks 0..1023, padded ETs) + xproj (1024..1279) ======
__global__ void k_seqxp(const float* __restrict__ ctx, const float* __restrict__ Ws,
                        const float* __restrict__ x, const float* __restrict__ WihxT,
                        const float* __restrict__ bih, const float* __restrict__ bhh,
                        unsigned short* __restrict__ ETsP, unsigned short* __restrict__ ctxb,
                        float* __restrict__ Xp) {
  __shared__ float sbuf[2688];
  const int tid = threadIdx.x;
  if (blockIdx.x < 1024) {
    const int b = blockIdx.x & 31;
    const int s0 = (blockIdx.x >> 5) * 16;
    for (int idx = tid; idx < 16 * HH; idx += 256) {
      float v = ctx[(size_t)(b * SS + s0) * HH + idx];
      sbuf[idx] = v;
      ctxb[(size_t)(b * SS + s0) * HH + idx] = f2bf(v);
    }
    __syncthreads();
    #pragma unroll
    for (int o = 0; o < 11; ++o) {
      int idx = o * 256 + tid;
      if (idx < 16 * HH) {
        int s = idx / HH, h = idx - s * HH;
        const float* cr = &sbuf[s * HH];
        float acc = 0.f;
        #pragma unroll 4
        for (int c = 0; c < HH; ++c) acc = fmaf(cr[c], Ws[c * HH + h], acc);
        int hg = h / RPB, ho = h - hg * RPB;
        ETsP[(size_t)(b * SS + s0 + s) * EP + hg * 24 + ho] = f2bf(__expf(2.f * acc));
      }
    }
  } else {
    const int r = blockIdx.x - 1024;
    const int t0 = (r & 7) * 8;
    const int b = r >> 3;
    for (int idx = tid; idx < 8 * ID; idx += 256)
      sbuf[idx] = x[(size_t)(b * TT + t0) * ID + idx];
    __syncthreads();
    for (int i = tid; i < G4; i += 256) {
      float bias = bih[i] + bhh[i];
      float acc[8];
      #pragma unroll
      for (int tt = 0; tt < 8; ++tt) acc[tt] = bias;
      for (int k = 0; k < ID; ++k) {
        float w = WihxT[k * G4 + i];
        #pragma unroll
        for (int tt = 0; tt < 8; ++tt) acc[tt] += sbuf[tt * ID + k] * w;
      }
      #pragma unroll
      for (int tt = 0; tt < 8; ++tt)
        Xp[(size_t)(b * TT + t0 + tt) * G4 + i] = acc[tt];
    }
  }
}

// ============ recurrence: 128 blocks, TWO batches per block, tag sync ========
__global__ __launch_bounds__(512, 1) void k_recur(
    const int* __restrict__ lens, const float* __restrict__ attb,
    const float* __restrict__ attv, const float* __restrict__ WgT,
    const unsigned short* __restrict__ WxS, const unsigned short* __restrict__ ETsP,
    const unsigned short* __restrict__ ctxb, const float* __restrict__ Xp,
    u64* __restrict__ Abuf, u64* __restrict__ Pbuf,
    unsigned* __restrict__ hallA) {
  const int p = blockIdx.x & 15;
  const int j = blockIdx.x >> 4;
  const int b0 = 2 * p, b1 = 2 * p + 1;
  const int tid = threadIdx.x;

  __shared__ float WgL[KK][WKP];            // 118272 B, shared by both batches
  __shared__ unsigned short WxL[RPB][HH];   // 7056 B
  __shared__ float scratch[512];
  __shared__ float redH[2][504], redC[2][504];
  __shared__ float gE[2][HH], hsh[2][HH], attn[2][HH];
  __shared__ float abL[HH], vL[HH];
  __shared__ float esh[2][SBLK], wsum[2][8];
  __shared__ float hLoc[2][RPB], cLoc[2][RPB];
  __shared__ float sumv_s, bsum_s[2];

  {
    const f32x4* src = (const f32x4*)(WgT + (size_t)j * KK * WKP);
    f32x4* dst = (f32x4*)WgL;
    for (int i = tid; i < KK * WKP / 4; i += 512) dst[i] = src[i];
  }
  for (int i = tid; i < RPB * HH; i += 512)
    ((unsigned short*)WxL)[i] = WxS[(size_t)j * RPB * HH + i];
  if (tid < HH) { abL[tid] = attb[tid]; vL[tid] = attv[tid]; }
  if (tid < RPB) { cLoc[0][tid] = 0.f; cLoc[1][tid] = 0.f; }
  __syncthreads();
  if (tid == 0) {
    float s = 0.f;
    for (int h = 0; h < HH; ++h) s += vL[h];
    sumv_s = s;
  }
  const int len0 = lens[b0], len1 = lens[b1];
  const int sbase = j * SBLK;
  u64* Am[2] = { Abuf + (size_t)(b0 * NJ + j) * LSLOT, Abuf + (size_t)(b1 * NJ + j) * LSLOT };
  u64* Pm[2] = { Pbuf + (size_t)(b0 * NJ + j) * LSLOT, Pbuf + (size_t)(b1 * NJ + j) * LSLOT };
  __syncthreads();

  for (int t = 0; t < TT; ++t) {
    // ---- Xp prefetch for both batches (2 rows/thread each)
    float xa0[4] = {0,0,0,0}, xb0[4] = {0,0,0,0};
    float xa1[4] = {0,0,0,0}, xb1[4] = {0,0,0,0};
    if (tid < 11) {
      const float* xp0 = Xp + ((size_t)b0 * TT + t) * G4 + j * RPB;
      const float* xp1 = Xp + ((size_t)b1 * TT + t) * G4 + j * RPB;
      int r0 = 2 * tid, r1 = r0 + 1;
      #pragma unroll
      for (int q = 0; q < 4; ++q) xa0[q] = xp0[q * HH + r0];
      #pragma unroll
      for (int q = 0; q < 4; ++q) xa1[q] = xp1[q * HH + r0];
      if (r1 < RPB) {
        #pragma unroll
        for (int q = 0; q < 4; ++q) xb0[q] = xp0[q * HH + r1];
        #pragma unroll
        for (int q = 0; q < 4; ++q) xb1[q] = xp1[q * HH + r1];
      }
    }

    // ---- lambdas for per-batch phases (bi is always a literal at call sites)
    auto pollA = [&](int bb, int bi) {
      if (tid < HH) {
        float a = abL[tid], hv = 0.f;
        if (t > 0) {
          const unsigned want = (unsigned)t;
          const int jh = tid / RPB, hr = tid - jh * RPB;
          u64 va[9];
          int g = 0;
          for (;;) {
            #pragma unroll
            for (int jj = 0; jj < NJ; ++jj)
              va[jj] = loadv(&Abuf[(size_t)(bb * NJ + jj) * LSLOT + tid]);
            va[8] = loadv(&Abuf[(size_t)(bb * NJ + jh) * LSLOT + HH + hr]);
            bool ok = true;
            #pragma unroll
            for (int q = 0; q < 9; ++q) ok &= (hi_u(va[q]) >= want);
            if (ok) break;
            __builtin_amdgcn_s_sleep(1);
            if (++g > (1 << 24)) break;
          }
          #pragma unroll
          for (int jj = 0; jj < NJ; ++jj) a += lo_f(va[jj]);
          hv = lo_f(va[8]);
        }
        gE[bi][tid] = __expf(2.f * a);
        hsh[bi][tid] = hv;
      }
    };
    auto phaseB = [&](int bb, int bi, int lenb) {
      int w = tid >> 6, lane = tid & 63;
      int sl = w * 8 + (lane >> 3);
      int hg = lane & 7;
      const uint4* ep4 = (const uint4*)(ETsP + ((size_t)(bb * SS + sbase + sl) * EP + hg * 24));
      union { uint4 q[3]; unsigned short s[24]; } eu;
      eu.q[0] = ep4[0]; eu.q[1] = ep4[1]; eu.q[2] = ep4[2];
      const int hb = hg * RPB;
      float ep = 0.f;
      #pragma unroll 7
      for (int i = 0; i < RPB; ++i)
        ep += vL[hb + i] * rcpf(fmaf(gE[bi][hb + i], bf2f(eu.s[i]), 1.f));
      ep += __shfl_xor(ep, 1); ep += __shfl_xor(ep, 2); ep += __shfl_xor(ep, 4);
      float eh = (sbase + sl < lenb) ? __expf(sumv_s - 2.f * ep) : 0.f;
      float ws = (hg == 0) ? eh : 0.f;
      ws += __shfl_xor(ws, 8); ws += __shfl_xor(ws, 16); ws += __shfl_xor(ws, 32);
      if (lane == 0) wsum[bi][w] = ws;
      if (hg == 0) esh[bi][sl] = eh;
    };
    auto phaseC = [&](int bb, int bi) {
      if (tid < 504) {
        int c = tid % HH, ch = tid / HH;
        const unsigned short* cb = ctxb + ((size_t)bb * SS + sbase) * HH + c;
        float pp = 0.f;
        for (int s = ch; s < SBLK; s += 3)
          pp = fmaf(esh[bi][s], bf2f(cb[(size_t)s * HH]), pp);
        scratch[ch * HH + c] = pp;
      } else if (tid == 504) {
        float bs = 0.f;
        #pragma unroll
        for (int w = 0; w < 8; ++w) bs += wsum[bi][w];
        bsum_s[bi] = bs;
      }
    };
    auto postP = [&](int bi) {
      if (tid < HH) {
        float pp = scratch[tid] + scratch[HH + tid] + scratch[2 * HH + tid];
        postv(&Pm[bi][tid], packft(pp, (unsigned)(t + 1)));
      } else if (tid == HH) {
        postv(&Pm[bi][HH], packft(bsum_s[bi], (unsigned)(t + 1)));
      }
    };
    auto phaseDh = [&](int bi) {
      if (tid < 504) {
        int col = tid % CPB, kc = tid / CPB;
        int k0 = HH + kc * 28;
        float acc = 0.f;
        #pragma unroll 7
        for (int i = 0; i < 28; ++i)
          acc = fmaf(WgL[k0 + i][col], hsh[bi][kc * 28 + i], acc);
        redH[bi][kc * CPB + col] = acc;
      }
    };
    auto pollP = [&](int bb, int bi, int base) {
      int i = tid - base;
      if (i >= 0 && i < HH) {
        const unsigned want = (unsigned)(t + 1);
        u64 pv[NJ], bv[NJ];
        int g = 0;
        for (;;) {
          #pragma unroll
          for (int jj = 0; jj < NJ; ++jj) {
            const u64* pb = Pbuf + (size_t)(bb * NJ + jj) * LSLOT;
            pv[jj] = loadv(&pb[i]);
            bv[jj] = loadv(&pb[HH]);
          }
          bool ok = true;
          #pragma unroll
          for (int jj = 0; jj < NJ; ++jj) ok &= (hi_u(pv[jj]) >= want) & (hi_u(bv[jj]) >= want);
          if (ok) break;
          __builtin_amdgcn_s_sleep(1);
          if (++g > (1 << 24)) break;
        }
        float s = 0.f, den = 0.f;
        #pragma unroll
        for (int jj = 0; jj < NJ; ++jj) { s += lo_f(pv[jj]); den += lo_f(bv[jj]); }
        attn[bi][i] = s * rcpf(den);
      }
    };
    auto phaseDc = [&](int bi) {
      if (tid < 504) {
        int col = tid % CPB, kc = tid / CPB;
        int k0 = kc * 28;
        float acc = 0.f;
        #pragma unroll 7
        for (int i = 0; i < 28; ++i)
          acc = fmaf(WgL[k0 + i][col], attn[bi][k0 + i], acc);
        redC[bi][kc * CPB + col] = acc;
      }
    };
    auto lstm = [&](int bb, int bi, const float* xa, const float* xb) {
      if (tid < 12) {
        size_t hrow = ((size_t)bb * TT + t) * HROW + j * 12;
        if (tid < 11) {
          const int r0 = 2 * tid, r1 = r0 + 1;
          float g0 = xa[0], g1 = xa[1], g2 = xa[2], g3 = xa[3];
          #pragma unroll
          for (int kc = 0; kc < 6; ++kc) {
            const float* rh = &redH[bi][kc * CPB];
            const float* rc = &redC[bi][kc * CPB];
            g0 += rh[r0] + rc[r0];
            g1 += rh[RPB + r0] + rc[RPB + r0];
            g2 += rh[2 * RPB + r0] + rc[2 * RPB + r0];
            g3 += rh[3 * RPB + r0] + rc[3 * RPB + r0];
          }
          float si = rcpf(1.f + __expf(-g0));
          float sf = rcpf(1.f + __expf(-g1));
          float tg = 1.f - 2.f * rcpf(1.f + __expf(2.f * g2));
          float so = rcpf(1.f + __expf(-g3));
          float cn = fmaf(sf, cLoc[bi][r0], si * tg);
          float tc = 1.f - 2.f * rcpf(1.f + __expf(2.f * cn));
          float h0 = so * tc;
          cLoc[bi][r0] = cn; hLoc[bi][r0] = h0;
          unsigned hv = (unsigned)f2bf(h0);
          if (r1 < RPB) {
            float G0 = xb[0], G1 = xb[1], G2 = xb[2], G3 = xb[3];
            #pragma unroll
            for (int kc = 0; kc < 6; ++kc) {
              const float* rh = &redH[bi][kc * CPB];
              const float* rc = &redC[bi][kc * CPB];
              G0 += rh[r1] + rc[r1];
              G1 += rh[RPB + r1] + rc[RPB + r1];
              G2 += rh[2 * RPB + r1] + rc[2 * RPB + r1];
              G3 += rh[3 * RPB + r1] + rc[3 * RPB + r1];
            }
            float Si = rcpf(1.f + __expf(-G0));
            float Sf = rcpf(1.f + __expf(-G1));
            float Tg = 1.f - 2.f * rcpf(1.f + __expf(2.f * G2));
            float So = rcpf(1.f + __expf(-G3));
            float Cn = fmaf(Sf, cLoc[bi][r1], Si * Tg);
            float Tc = 1.f - 2.f * rcpf(1.f + __expf(2.f * Cn));
            float h1 = So * Tc;
            cLoc[bi][r1] = Cn; hLoc[bi][r1] = h1;
            hv |= ((unsigned)f2bf(h1)) << 16;
          }
          postu(&hallA[hrow + tid], hv);
        } else {
          postu(&hallA[hrow + 11], 0u);
        }
      }
    };
    auto aGemv = [&](int bi) {
      if (tid < HH) {
        float acc = 0.f;
        #pragma unroll
        for (int r = 0; r < RPB; ++r)
          acc = fmaf(hLoc[bi][r], bf2f(WxL[r][tid]), acc);
        postv(&Am[bi][tid], packft(acc, (unsigned)(t + 1)));
      } else if (tid < HH + RPB) {
        postv(&Am[bi][tid], packft(hLoc[bi][tid - HH], (unsigned)(t + 1)));
      }
    };

    // ---- interleaved schedule: polls covered by the other batch's compute
    pollA(b0, 0);
    __syncthreads();                           // BAR1
    phaseB(b0, 0, len0);
    __syncthreads();                           // BAR2
    phaseC(b0, 0);
    __syncthreads();                           // BAR3
    postP(0);
    phaseDh(0);
    pollA(b1, 1);                              // b1's producers posted ~1 step's tail ago
    __syncthreads();                           // BAR4
    phaseB(b1, 1, len1);
    __syncthreads();                           // BAR5
    phaseC(b1, 1);
    __syncthreads();                           // BAR6
    postP(1);
    phaseDh(1);
    pollP(b0, 0, 0);                           // P0 posted ~2 phases ago
    __syncthreads();                           // BAR7
    phaseDc(0);
    __syncthreads();                           // BAR8
    lstm(b0, 0, xa0, xb0);
    __syncthreads();                           // BAR9
    aGemv(0);                                  // waves 0-2
    pollP(b1, 1, 256);                         // waves 4-6, concurrent
    __syncthreads();                           // BAR10
    phaseDc(1);
    __syncthreads();                           // BAR11
    lstm(b1, 1, xa1, xb1);
    __syncthreads();                           // BAR12
    aGemv(1);
  }
}

// ============ decode GEMM: standalone, 256x256 tiles, 2 blocks/CU ============
__global__ __launch_bounds__(512) void k_decode(const unsigned* __restrict__ hallA,
                                                const unsigned short* __restrict__ wdb,
                                                float* __restrict__ out) {
  __shared__ __align__(16) unsigned short As[256 * LP];
  __shared__ __align__(16) unsigned short Bs[256 * LP];
  const unsigned short* hallS = (const unsigned short*)hallA;
  const int tid = threadIdx.x;
  const int n0 = blockIdx.x * 256, m0 = blockIdx.y * 256;
  const int lane = tid & 63, wid = tid >> 6;
  const int wm = wid >> 2, wn = wid & 3;
  const int lr = lane & 15, lk = lane >> 4;
  f32x4 acc[8][4];
  #pragma unroll
  for (int i = 0; i < 8; ++i)
    #pragma unroll
    for (int jj = 0; jj < 4; ++jj) acc[i][jj] = (f32x4)0.f;

  for (int k0 = 0; k0 < KP; k0 += 64) {
    if (k0) __syncthreads();
    #pragma unroll
    for (int i = 0; i < 4; ++i) {
      int flat = i * 512 + tid;
      int row = flat >> 3;
      int c8 = flat & 7;
      uint4 va = *(const uint4*)(hallS + (size_t)(m0 + row) * KP + k0 + c8 * 8);
      *(uint4*)&As[row * LP + c8 * 8] = va;
      uint4 vb = *(const uint4*)(wdb + (size_t)(n0 + row) * KP + k0 + c8 * 8);
      *(uint4*)&Bs[row * LP + c8 * 8] = vb;
    }
    __syncthreads();
    #pragma unroll
    for (int kk = 0; kk < 64; kk += 32) {
      bf16x8 af[8], bfr[4];
      #pragma unroll
      for (int mi = 0; mi < 8; ++mi)
        af[mi] = *(const bf16x8*)&As[(wm * 128 + mi * 16 + lr) * LP + kk + lk * 8];
      #pragma unroll
      for (int ni = 0; ni < 4; ++ni)
        bfr[ni] = *(const bf16x8*)&Bs[(wn * 64 + ni * 16 + lr) * LP + kk + lk * 8];
      #pragma unroll
      for (int mi = 0; mi < 8; ++mi)
        #pragma unroll
        for (int ni = 0; ni < 4; ++ni)
          acc[mi][ni] = __builtin_amdgcn_mfma_f32_16x16x32_bf16(
              af[mi], bfr[ni], acc[mi][ni], 0, 0, 0);
    }
  }
  #pragma unroll
  for (int mi = 0; mi < 8; ++mi)
    #pragma unroll
    for (int ni = 0; ni < 4; ++ni) {
      int col = n0 + wn * 64 + ni * 16 + lr;
      if (col < VV) {
        #pragma unroll
        for (int r = 0; r < 4; ++r) {
          int row = m0 + wm * 128 + mi * 16 + lk * 4 + r;
          out[(size_t)row * VV + col] = acc[mi][ni][r];
        }
      }
    }
}

extern "C" void kernel_launch(void* const* d_in, const int* in_sizes, int n_in,
                              void* d_out, int out_size, void* d_ws, size_t ws_size,
                              hipStream_t stream) {
  (void)in_sizes; (void)n_in; (void)out_size; (void)ws_size;
  const float* x     = (const float*)d_in[0];
  const float* ctx   = (const float*)d_in[1];
  const int*   lens  = (const int*)d_in[2];
  const float* Wih   = (const float*)d_in[3];
  const float* Whh   = (const float*)d_in[4];
  const float* bih   = (const float*)d_in[5];
  const float* bhh   = (const float*)d_in[6];
  const float* attWx = (const float*)d_in[7];
  const float* attWs = (const float*)d_in[8];
  const float* attb  = (const float*)d_in[9];
  const float* attv  = (const float*)d_in[10];
  const float* Wdec  = (const float*)d_in[11];
  float* out = (float*)d_out;

  char* base = (char*)d_ws;
  size_t off = 0;
  auto alloc = [&](size_t bytes) -> void* {
    off = (off + 255) & ~(size_t)255;
    void* p = base + off;
    off += bytes;
    return p;
  };
  unsigned short* ETsP = (unsigned short*)alloc((size_t)BB * SS * EP * 2);
  unsigned short* ctxb = (unsigned short*)alloc((size_t)BB * SS * HH * 2);
  float*          Xp   = (float*)alloc((size_t)BB * TT * G4 * 4);
  float*          WihxT= (float*)alloc((size_t)ID * G4 * 4);
  unsigned*       hallA= (unsigned*)alloc((size_t)BB * TT * HROW * 4);
  unsigned short* Wdb  = (unsigned short*)alloc((size_t)NP2 * KP * 2);
  float*          WgT  = (float*)alloc((size_t)NJ * KK * WKP * 4);
  unsigned short* WxS  = (unsigned short*)alloc((size_t)NJ * RPB * HH * 2);
  u64*            Abuf = (u64*)alloc((size_t)BB * NJ * LSLOT * 8);
  u64*            Pbuf = (u64*)alloc((size_t)BB * NJ * LSLOT * 8);

  {
    const int TOTP = NJ * KK * WKP + NJ * RPB * HH + 2 * BB * NJ * LSLOT;
    const int NBP = (TOTP + 255) / 256;
    k_prepall<<<dim3(NB_WDEC + NB_TR + NBP), dim3(256), 0, stream>>>(
        Wih, Whh, attWx, Wdec, WihxT, Wdb, WgT, WxS, Abuf, Pbuf);
  }
  k_seqxp<<<dim3(1024 + 256), dim3(256), 0, stream>>>(ctx, attWs, x, WihxT,
                                                      bih, bhh, ETsP, ctxb, Xp);
  {
    const int* a0 = lens; const float* a1 = attb; const float* a2 = attv;
    const float* a3 = WgT; const unsigned short* a4 = WxS;
    const unsigned short* a5 = ETsP; const unsigned short* a6 = ctxb;
    const float* a7 = Xp; u64* a8 = Abuf; u64* a9 = Pbuf;
    unsigned* a10 = hallA;
    void* args[] = { &a0, &a1, &a2, &a3, &a4, &a5, &a6, &a7, &a8, &a9, &a10 };
    hipLaunchCooperativeKernel((void*)k_recur, dim3(BB * NJ / 2), dim3(512), args, 0, stream);
  }
  k_decode<<<dim3(NTN, 8), dim3(512), 0, stream>>>(hallA, Wdb, out);
}

// Round 10
// 878.777 us; speedup vs baseline: 1.5108x; 1.5108x over previous
//
#include <hip/hip_runtime.h>
#include <stdint.h>

#define BB 32
#define TT 64
#define ID 300
#define HH 168
#define SS 512
#define VV 50257
#define G4 672     // 4*H
#define IC 468     // I + C
#define KP 192     // K padded (8 regions x 24, k-permuted)
#define NP2 50432  // V padded to 256 (197 tiles)
#define NJ 8       // blocks per batch
#define RPB 21     // h rows per block
#define CPB 84     // gate cols per block
#define KK 336     // gate K dim
#define WKP 88     // WgT col pad
#define EPAD 170   // ETs LDS row pad (85 dwords, gcd(85,32)=1)
#define SBLK 64    // s positions per block
#define LSLOT 192  // u64 slots per (b,j) bucket
#define HROW 96    // u32 per hall row (KP/2)
#define LP 72      // decode LDS row pad in shorts
#define NTN 197    // decode n-tiles (50432/256)

typedef float f32x4 __attribute__((ext_vector_type(4)));
typedef short bf16x8 __attribute__((ext_vector_type(8)));
typedef unsigned long long u64;

__device__ __forceinline__ float bf2f(unsigned short u) {
  union { unsigned int i; float f; } v; v.i = ((unsigned int)u) << 16; return v.f;
}
__device__ __forceinline__ unsigned short f2bf(float f) {
  union { float f; unsigned int u; } v; v.f = f;
  unsigned int r = v.u + 0x7fffu + ((v.u >> 16) & 1u);
  return (unsigned short)(r >> 16);
}
__device__ __forceinline__ float rcpf(float x) { return __builtin_amdgcn_rcpf(x); }
__device__ __forceinline__ u64 packft(float f, unsigned tag) {
  union { float f; unsigned u; } v; v.f = f;
  return ((u64)tag << 32) | (u64)v.u;
}
__device__ __forceinline__ float lo_f(u64 x) {
  union { unsigned u; float f; } v; v.u = (unsigned)x; return v.f;
}
__device__ __forceinline__ unsigned hi_u(u64 x) { return (unsigned)(x >> 32); }
__device__ __forceinline__ void postv(u64* p, u64 v) {
  __hip_atomic_store(p, v, __ATOMIC_RELAXED, __HIP_MEMORY_SCOPE_AGENT);
}
__device__ __forceinline__ u64 loadv(const u64* p) {
  return __hip_atomic_load(p, __ATOMIC_RELAXED, __HIP_MEMORY_SCOPE_AGENT);
}
__device__ __forceinline__ void postu(unsigned* p, unsigned v) {
  __hip_atomic_store(p, v, __ATOMIC_RELAXED, __HIP_MEMORY_SCOPE_AGENT);
}

// ============ single merged prep kernel ======================================
// ranges: [0,NB_WDEC) Wdb | [.,+NB_Z) WgT/WxS/zero | [.,+1024) seqproj | [.,+256) xproj
#define NB_WDEC 4728   // NP2*KP/8/256
#define NB_Z    1419   // ceil((236544+28224+98304)/256)
__global__ void k_prep(const float* __restrict__ Wih, const float* __restrict__ Whh,
                       const float* __restrict__ attWx, const float* __restrict__ Wd,
                       const float* __restrict__ ctx, const float* __restrict__ attWs,
                       const float* __restrict__ x, const float* __restrict__ bih,
                       const float* __restrict__ bhh,
                       unsigned short* __restrict__ Wdb, float* __restrict__ WgT,
                       unsigned short* __restrict__ WxS, u64* __restrict__ Abuf,
                       u64* __restrict__ Pbuf, unsigned short* __restrict__ ETs,
                       unsigned short* __restrict__ ctxb, float* __restrict__ Xp) {
  const int bid = blockIdx.x, tid = threadIdx.x;
  __shared__ float sbuf[2688];
  if (bid < NB_WDEC) {
    // Wdb[v][kp]: region rg = kp/24, off = kp%24; kreal = rg*21+off (off<21), else 0
    size_t e0 = ((size_t)bid * 256 + tid) * 8;
    int v = (int)(e0 / KP), kp0 = (int)(e0 - (size_t)v * KP);
    int rg = kp0 / 24, off0 = kp0 - rg * 24;   // off0 in {0,8,16}
    unsigned short o[8];
    if (v < VV) {
      const float* src = Wd + (size_t)v * HH + rg * RPB + off0;
      #pragma unroll
      for (int i = 0; i < 8; ++i) o[i] = (off0 + i < RPB) ? f2bf(src[i]) : 0;
    } else {
      #pragma unroll
      for (int i = 0; i < 8; ++i) o[i] = 0;
    }
    *(uint4*)(Wdb + e0) = *(const uint4*)o;
    return;
  }
  int b2 = bid - NB_WDEC;
  if (b2 < NB_Z) {
    int idx = b2 * 256 + tid;
    const int T1 = NJ * KK * WKP;             // 236544
    const int T2 = T1 + NJ * RPB * HH;        // 264768
    const int ZH = BB * NJ * LSLOT;           // 49152
    const int T3 = T2 + 2 * ZH;               // 363072
    if (idx < T1) {
      int j = idx / (KK * WKP); int r = idx - j * (KK * WKP);
      int k = r / WKP, col = r - k * WKP;
      float w = 0.f;
      if (col < CPB) {
        int gt = col / RPB, rr = col - gt * RPB;
        int gcol = gt * HH + j * RPB + rr;
        w = (k < HH) ? Wih[(size_t)gcol * IC + ID + k] : Whh[(size_t)gcol * HH + (k - HH)];
      }
      WgT[idx] = w;
    } else if (idx < T2) {
      int r = idx - T1;
      WxS[r] = f2bf(attWx[r]);
    } else if (idx < T3) {
      int r = idx - T2;
      if (r < ZH) Abuf[r] = 0ull;
      else        Pbuf[r - ZH] = 0ull;
    }
    return;
  }
  b2 -= NB_Z;
  if (b2 < 1024) {
    // seqproj: ETs[b][s][h] = bf16(exp(2P)), ctxb = bf16(ctx)
    const int b = b2 & 31;
    const int s0 = (b2 >> 5) * 16;
    for (int idx = tid; idx < 16 * HH; idx += 256) {
      float v = ctx[(size_t)(b * SS + s0) * HH + idx];
      sbuf[idx] = v;
      ctxb[(size_t)(b * SS + s0) * HH + idx] = f2bf(v);
    }
    __syncthreads();
    #pragma unroll
    for (int o = 0; o < 11; ++o) {
      int idx = o * 256 + tid;
      if (idx < 16 * HH) {
        int s = idx / HH, h = idx - s * HH;
        const float* cr = &sbuf[s * HH];
        float acc = 0.f;
        #pragma unroll 4
        for (int c = 0; c < HH; ++c) acc = fmaf(cr[c], attWs[c * HH + h], acc);
        ETs[(size_t)(b * SS + s0 + s) * HH + h] = f2bf(__expf(2.f * acc));
      }
    }
    return;
  }
  b2 -= 1024;
  {
    // xproj: Xp[b][t][i] = x@Wih_x^T + b_ih + b_hh (Wih rows read directly)
    const int t0 = (b2 & 7) * 8;
    const int b = b2 >> 3;
    for (int idx = tid; idx < 8 * ID; idx += 256)
      sbuf[idx] = x[(size_t)(b * TT + t0) * ID + idx];
    __syncthreads();
    for (int i = tid; i < G4; i += 256) {
      float bias = bih[i] + bhh[i];
      float acc[8];
      #pragma unroll
      for (int tt = 0; tt < 8; ++tt) acc[tt] = bias;
      const f32x4* wr = (const f32x4*)(Wih + (size_t)i * IC);  // row 16B-aligned (468*4)
      for (int k4 = 0; k4 < ID / 4; ++k4) {
        f32x4 w = wr[k4];
        #pragma unroll
        for (int tt = 0; tt < 8; ++tt) {
          const float* xr = &sbuf[tt * ID + k4 * 4];
          acc[tt] += xr[0] * w[0] + xr[1] * w[1] + xr[2] * w[2] + xr[3] * w[3];
        }
      }
      #pragma unroll
      for (int tt = 0; tt < 8; ++tt)
        Xp[(size_t)(b * TT + t0 + tt) * G4 + i] = acc[tt];
    }
  }
}

// ============ recurrence: R8 structure (477us), 256 blocks, tag sync =========
__global__ __launch_bounds__(512, 1) void k_recur(
    const int* __restrict__ lens, const float* __restrict__ attb,
    const float* __restrict__ attv, const float* __restrict__ WgT,
    const unsigned short* __restrict__ WxS, const unsigned short* __restrict__ ETs,
    const unsigned short* __restrict__ ctxb, const float* __restrict__ Xp,
    u64* __restrict__ Abuf, u64* __restrict__ Pbuf,
    unsigned* __restrict__ hallA) {
  const int b = blockIdx.x & 31;
  const int j = blockIdx.x >> 5;
  const int tid = threadIdx.x;

  __shared__ float WgL[KK][WKP];            // 118272 B, [k][col]
  __shared__ unsigned short EL[SBLK][EPAD]; // 21760 B
  __shared__ unsigned short WxL[RPB][HH];   // 7056 B
  __shared__ float scratch[512];
  __shared__ float redH[504], redC[504];
  __shared__ float gE[HH], hsh[HH], abL[HH], vL[HH], attn[HH];
  __shared__ float esh[SBLK], hLoc[RPB], cLoc[RPB], wsum[8];
  __shared__ float sumv_s, bsum_s;

  {
    const f32x4* src = (const f32x4*)(WgT + (size_t)j * KK * WKP);
    f32x4* dst = (f32x4*)WgL;
    for (int i = tid; i < KK * WKP / 4; i += 512) dst[i] = src[i];
  }
  for (int i = tid; i < SBLK * HH; i += 512) {
    int s = i / HH, h = i - s * HH;
    EL[s][h] = ETs[((size_t)b * SS + j * SBLK + s) * HH + h];
  }
  for (int i = tid; i < RPB * HH; i += 512)
    ((unsigned short*)WxL)[i] = WxS[(size_t)j * RPB * HH + i];
  if (tid < HH) { abL[tid] = attb[tid]; vL[tid] = attv[tid]; }
  if (tid < RPB) cLoc[tid] = 0.f;
  __syncthreads();
  if (tid == 0) {
    float s = 0.f;
    for (int h = 0; h < HH; ++h) s += vL[h];
    sumv_s = s;
  }
  const int len = lens[b];
  const int sbase = j * SBLK;
  u64* Amine = Abuf + (size_t)(b * NJ + j) * LSLOT;
  u64* Pmine = Pbuf + (size_t)(b * NJ + j) * LSLOT;
  __syncthreads();

  for (int t = 0; t < TT; ++t) {
    // ---- Xp prefetch (2 rows/thread for the 11-thread LSTM)
    float xa0=0,xa1=0,xa2=0,xa3=0, xb0=0,xb1=0,xb2=0,xb3=0;
    if (tid < 11) {
      const float* xp = Xp + ((size_t)b * TT + t) * G4 + j * RPB;
      int r0 = 2 * tid, r1 = r0 + 1;
      xa0 = xp[r0]; xa1 = xp[HH + r0]; xa2 = xp[2*HH + r0]; xa3 = xp[3*HH + r0];
      if (r1 < RPB) { xb0 = xp[r1]; xb1 = xp[HH + r1]; xb2 = xp[2*HH + r1]; xb3 = xp[3*HH + r1]; }
    }
    // ---- gE + hsh: poll tag-embedded a-partials (8) + h value (1)
    if (tid < HH) {
      float a = abL[tid], hv = 0.f;
      if (t > 0) {
        const unsigned want = (unsigned)t;
        const int jh = tid / RPB, hr = tid - jh * RPB;
        u64 va[9];
        int g = 0;
        for (;;) {
          #pragma unroll
          for (int jj = 0; jj < NJ; ++jj)
            va[jj] = loadv(&Abuf[(size_t)(b * NJ + jj) * LSLOT + tid]);
          va[8] = loadv(&Abuf[(size_t)(b * NJ + jh) * LSLOT + HH + hr]);
          bool ok = true;
          #pragma unroll
          for (int q = 0; q < 9; ++q) ok &= (hi_u(va[q]) >= want);
          if (ok) break;
          __builtin_amdgcn_s_sleep(1);
          if (++g > (1 << 24)) break;
        }
        #pragma unroll
        for (int jj = 0; jj < NJ; ++jj) a += lo_f(va[jj]);
        hv = lo_f(va[8]);
      }
      gE[tid] = __expf(2.f * a);
      hsh[tid] = hv;
    }
    __syncthreads();                                     // BAR A
    // ---- B + softmax (wave-local)
    {
      int w = tid >> 6, lane = tid & 63;
      int sl = w * 8 + (lane >> 3);
      int hg = lane & 7;
      const unsigned short* er = &EL[sl][hg * RPB];
      const int hb = hg * RPB;
      float ep = 0.f;
      #pragma unroll 7
      for (int i = 0; i < RPB; ++i)
        ep += vL[hb + i] * rcpf(fmaf(gE[hb + i], bf2f(er[i]), 1.f));
      ep += __shfl_xor(ep, 1); ep += __shfl_xor(ep, 2); ep += __shfl_xor(ep, 4);
      float eh = (sbase + sl < len) ? __expf(sumv_s - 2.f * ep) : 0.f;
      float ws = (hg == 0) ? eh : 0.f;
      ws += __shfl_xor(ws, 8); ws += __shfl_xor(ws, 16); ws += __shfl_xor(ws, 32);
      if (lane == 0) wsum[w] = ws;
      if (hg == 0) esh[sl] = eh;
    }
    __syncthreads();                                     // BAR B
    // ---- C partials + bsum
    if (tid < 504) {
      int c = tid % HH, ch = tid / HH;
      const unsigned short* cb = ctxb + ((size_t)b * SS + sbase) * HH + c;
      float p = 0.f;
      for (int s = ch; s < SBLK; s += 3)
        p = fmaf(esh[s], bf2f(cb[(size_t)s * HH]), p);
      scratch[ch * HH + c] = p;
    } else if (tid == 504) {
      float bs = 0.f;
      #pragma unroll
      for (int w = 0; w < 8; ++w) bs += wsum[w];
      bsum_s = bs;
    }
    __syncthreads();                                     // BAR C
    // ---- post P (tag-embedded)
    if (tid < HH) {
      float p = scratch[tid] + scratch[HH + tid] + scratch[2 * HH + tid];
      postv(&Pmine[tid], packft(p, (unsigned)(t + 1)));
    } else if (tid == HH) {
      postv(&Pmine[HH], packft(bsum_s, (unsigned)(t + 1)));
    }
    // ---- D_h (overlaps P propagation)
    if (tid < 504) {
      int col = tid % CPB, kc = tid / CPB;
      int k0 = HH + kc * 28;
      float acc = 0.f;
      #pragma unroll 7
      for (int i = 0; i < 28; ++i)
        acc = fmaf(WgL[k0 + i][col], hsh[kc * 28 + i], acc);
      redH[kc * CPB + col] = acc;
    }
    // ---- attn finalize: poll p-lines directly
    if (tid < HH) {
      const unsigned want = (unsigned)(t + 1);
      u64 pv[NJ], bv[NJ];
      int g = 0;
      for (;;) {
        #pragma unroll
        for (int jj = 0; jj < NJ; ++jj) {
          const u64* pb = Pbuf + (size_t)(b * NJ + jj) * LSLOT;
          pv[jj] = loadv(&pb[tid]);
          bv[jj] = loadv(&pb[HH]);
        }
        bool ok = true;
        #pragma unroll
        for (int jj = 0; jj < NJ; ++jj) ok &= (hi_u(pv[jj]) >= want) & (hi_u(bv[jj]) >= want);
        if (ok) break;
        __builtin_amdgcn_s_sleep(1);
        if (++g > (1 << 24)) break;
      }
      float s = 0.f, den = 0.f;
      #pragma unroll
      for (int jj = 0; jj < NJ; ++jj) { s += lo_f(pv[jj]); den += lo_f(bv[jj]); }
      attn[tid] = s * rcpf(den);
    }
    __syncthreads();                                     // BAR D
    // ---- D_c
    if (tid < 504) {
      int col = tid % CPB, kc = tid / CPB;
      int k0 = kc * 28;
      float acc = 0.f;
      #pragma unroll 7
      for (int i = 0; i < 28; ++i)
        acc = fmaf(WgL[k0 + i][col], attn[k0 + i], acc);
      redC[kc * CPB + col] = acc;
    }
    __syncthreads();                                     // BAR E
    // ---- gates + LSTM: 11 threads x 2 rows; pack h pairs -> hallA u32 atomics
    if (tid < 12) {
      size_t hrow = ((size_t)b * TT + t) * HROW + j * 12;
      if (tid < 11) {
        const int r0 = 2 * tid, r1 = r0 + 1;
        float g0 = xa0, g1 = xa1, g2 = xa2, g3 = xa3;
        #pragma unroll
        for (int kc = 0; kc < 6; ++kc) {
          const float* rh = &redH[kc * CPB];
          const float* rc = &redC[kc * CPB];
          g0 += rh[r0] + rc[r0];
          g1 += rh[RPB + r0] + rc[RPB + r0];
          g2 += rh[2 * RPB + r0] + rc[2 * RPB + r0];
          g3 += rh[3 * RPB + r0] + rc[3 * RPB + r0];
        }
        float si = rcpf(1.f + __expf(-g0));
        float sf = rcpf(1.f + __expf(-g1));
        float tg = 1.f - 2.f * rcpf(1.f + __expf(2.f * g2));
        float so = rcpf(1.f + __expf(-g3));
        float cn = fmaf(sf, cLoc[r0], si * tg);
        float tc = 1.f - 2.f * rcpf(1.f + __expf(2.f * cn));
        float h0 = so * tc;
        cLoc[r0] = cn; hLoc[r0] = h0;
        unsigned hv = (unsigned)f2bf(h0);
        if (r1 < RPB) {
          float G0 = xb0, G1 = xb1, G2 = xb2, G3 = xb3;
          #pragma unroll
          for (int kc = 0; kc < 6; ++kc) {
            const float* rh = &redH[kc * CPB];
            const float* rc = &redC[kc * CPB];
            G0 += rh[r1] + rc[r1];
            G1 += rh[RPB + r1] + rc[RPB + r1];
            G2 += rh[2 * RPB + r1] + rc[2 * RPB + r1];
            G3 += rh[3 * RPB + r1] + rc[3 * RPB + r1];
          }
          float Si = rcpf(1.f + __expf(-G0));
          float Sf = rcpf(1.f + __expf(-G1));
          float Tg = 1.f - 2.f * rcpf(1.f + __expf(2.f * G2));
          float So = rcpf(1.f + __expf(-G3));
          float Cn = fmaf(Sf, cLoc[r1], Si * Tg);
          float Tc = 1.f - 2.f * rcpf(1.f + __expf(2.f * Cn));
          float h1 = So * Tc;
          cLoc[r1] = Cn; hLoc[r1] = h1;
          hv |= ((unsigned)f2bf(h1)) << 16;
        }
        postu(&hallA[hrow + tid], hv);
      } else {
        postu(&hallA[hrow + 11], 0u);
      }
    }
    __syncthreads();                                     // BAR F
    // ---- a = h_slice @ Wx_slice (168 thr x 21 FMA) + posts
    if (tid < HH) {
      float acc = 0.f;
      #pragma unroll
      for (int r = 0; r < RPB; ++r)
        acc = fmaf(hLoc[r], bf2f(WxL[r][tid]), acc);
      postv(&Amine[tid], packft(acc, (unsigned)(t + 1)));
    } else if (tid < HH + RPB) {
      postv(&Amine[tid], packft(hLoc[tid - HH], (unsigned)(t + 1)));
    }
  }
}

// ============ decode GEMM: 256x256 tiles, LDS-coalesced epilogue =============
__global__ __launch_bounds__(512) void k_decode(const unsigned* __restrict__ hallA,
                                                const unsigned short* __restrict__ wdb,
                                                float* __restrict__ out) {
  __shared__ __align__(16) unsigned short SM[2 * 256 * LP];  // 73728 B
  unsigned short* As = SM;
  unsigned short* Bs = SM + 256 * LP;
  const unsigned short* hallS = (const unsigned short*)hallA;
  const int tid = threadIdx.x;
  const int n0 = blockIdx.x * 256, m0 = blockIdx.y * 256;
  const int lane = tid & 63, wid = tid >> 6;
  const int wm = wid >> 2, wn = wid & 3;
  const int lr = lane & 15, lk = lane >> 4;
  f32x4 acc[8][4];
  #pragma unroll
  for (int i = 0; i < 8; ++i)
    #pragma unroll
    for (int jj = 0; jj < 4; ++jj) acc[i][jj] = (f32x4)0.f;

  for (int k0 = 0; k0 < KP; k0 += 64) {
    if (k0) __syncthreads();
    #pragma unroll
    for (int i = 0; i < 4; ++i) {
      int flat = i * 512 + tid;
      int row = flat >> 3;
      int c8 = flat & 7;
      uint4 va = *(const uint4*)(hallS + (size_t)(m0 + row) * KP + k0 + c8 * 8);
      *(uint4*)&As[row * LP + c8 * 8] = va;
      uint4 vb = *(const uint4*)(wdb + (size_t)(n0 + row) * KP + k0 + c8 * 8);
      *(uint4*)&Bs[row * LP + c8 * 8] = vb;
    }
    __syncthreads();
    #pragma unroll
    for (int kk = 0; kk < 64; kk += 32) {
      bf16x8 af[8], bfr[4];
      #pragma unroll
      for (int mi = 0; mi < 8; ++mi)
        af[mi] = *(const bf16x8*)&As[(wm * 128 + mi * 16 + lr) * LP + kk + lk * 8];
      #pragma unroll
      for (int ni = 0; ni < 4; ++ni)
        bfr[ni] = *(const bf16x8*)&Bs[(wn * 64 + ni * 16 + lr) * LP + kk + lk * 8];
      #pragma unroll
      for (int mi = 0; mi < 8; ++mi)
        #pragma unroll
        for (int ni = 0; ni < 4; ++ni)
          acc[mi][ni] = __builtin_amdgcn_mfma_f32_16x16x32_bf16(
              af[mi], bfr[ni], acc[mi][ni], 0, 0, 0);
    }
  }
  // ---- epilogue: 4 chunks of 64 rows x 256 cols via LDS, wave-contiguous out
  float* Cl = (float*)SM;   // 65536 B needed <= 73728
  for (int c = 0; c < 4; ++c) {
    __syncthreads();
    if (wm == (c >> 1)) {
      const int mib = (c & 1) * 4;
      #pragma unroll
      for (int m2 = 0; m2 < 4; ++m2) {
        #pragma unroll
        for (int ni = 0; ni < 4; ++ni) {
          #pragma unroll
          for (int r = 0; r < 4; ++r) {
            int lrow = m2 * 16 + lk * 4 + r;
            Cl[lrow * 256 + wn * 64 + ni * 16 + lr] = acc[mib + m2][ni][r];
          }
        }
      }
    }
    __syncthreads();
    const int rowbase = m0 + c * 64;
    #pragma unroll
    for (int q = 0; q < 32; ++q) {
      int idx = q * 512 + tid;
      int lrow = idx >> 8;
      int cc = idx & 255;
      int gcol = n0 + cc;
      if (gcol < VV)
        out[(size_t)(rowbase + lrow) * VV + gcol] = Cl[lrow * 256 + cc];
    }
  }
}

extern "C" void kernel_launch(void* const* d_in, const int* in_sizes, int n_in,
                              void* d_out, int out_size, void* d_ws, size_t ws_size,
                              hipStream_t stream) {
  (void)in_sizes; (void)n_in; (void)out_size; (void)ws_size;
  const float* x     = (const float*)d_in[0];
  const float* ctx   = (const float*)d_in[1];
  const int*   lens  = (const int*)d_in[2];
  const float* Wih   = (const float*)d_in[3];
  const float* Whh   = (const float*)d_in[4];
  const float* bih   = (const float*)d_in[5];
  const float* bhh   = (const float*)d_in[6];
  const float* attWx = (const float*)d_in[7];
  const float* attWs = (const float*)d_in[8];
  const float* attb  = (const float*)d_in[9];
  const float* attv  = (const float*)d_in[10];
  const float* Wdec  = (const float*)d_in[11];
  float* out = (float*)d_out;

  char* base = (char*)d_ws;
  size_t off = 0;
  auto alloc = [&](size_t bytes) -> void* {
    off = (off + 255) & ~(size_t)255;
    void* p = base + off;
    off += bytes;
    return p;
  };
  unsigned short* ETs  = (unsigned short*)alloc((size_t)BB * SS * HH * 2);
  unsigned short* ctxb = (unsigned short*)alloc((size_t)BB * SS * HH * 2);
  float*          Xp   = (float*)alloc((size_t)BB * TT * G4 * 4);
  unsigned*       hallA= (unsigned*)alloc((size_t)BB * TT * HROW * 4);
  unsigned short* Wdb  = (unsigned short*)alloc((size_t)NP2 * KP * 2);
  float*          WgT  = (float*)alloc((size_t)NJ * KK * WKP * 4);
  unsigned short* WxS  = (unsigned short*)alloc((size_t)NJ * RPB * HH * 2);
  u64*            Abuf = (u64*)alloc((size_t)BB * NJ * LSLOT * 8);
  u64*            Pbuf = (u64*)alloc((size_t)BB * NJ * LSLOT * 8);

  k_prep<<<dim3(NB_WDEC + NB_Z + 1024 + 256), dim3(256), 0, stream>>>(
      Wih, Whh, attWx, Wdec, ctx, attWs, x, bih, bhh,
      Wdb, WgT, WxS, Abuf, Pbuf, ETs, ctxb, Xp);
  {
    const int* a0 = lens; const float* a1 = attb; const float* a2 = attv;
    const float* a3 = WgT; const unsigned short* a4 = WxS;
    const unsigned short* a5 = ETs; const unsigned short* a6 = ctxb;
    const float* a7 = Xp; u64* a8 = Abuf; u64* a9 = Pbuf;
    unsigned* a10 = hallA;
    void* args[] = { &a0, &a1, &a2, &a3, &a4, &a5, &a6, &a7, &a8, &a9, &a10 };
    hipLaunchCooperativeKernel((void*)k_recur, dim3(BB * NJ), dim3(512), args, 0, stream);
  }
  k_decode<<<dim3(NTN, 8), dim3(512), 0, stream>>>(hallA, Wdb, out);
}

// Round 11
// 807.616 us; speedup vs baseline: 1.6439x; 1.0881x over previous
//
#include <hip/hip_runtime.h>
#include <stdint.h>

#define BB 32
#define TT 64
#define ID 300
#define HH 168
#define SS 512
#define VV 50257
#define G4 672     // 4*H
#define IC 468     // I + C
#define KP 192     // K padded for decode MFMA
#define NP2 50432  // V padded to 256 (197 tiles)
#define NJ 8       // blocks per batch
#define RPB 21     // h rows per block
#define CPB 84     // gate cols per block
#define KK 336     // gate K dim
#define WKP 88     // WgT col pad
#define EPAD 170   // ETs LDS row pad (85 dwords, gcd(85,32)=1)
#define SBLK 64    // s positions per block
#define LSLOT 192  // u64 slots per (b,j) bucket
#define LP 72      // decode LDS row pad in shorts
#define NTN 197    // decode n-tiles (50432/256)

typedef float f32x4 __attribute__((ext_vector_type(4)));
typedef short bf16x8 __attribute__((ext_vector_type(8)));
typedef unsigned long long u64;

__device__ __forceinline__ float bf2f(unsigned short u) {
  union { unsigned int i; float f; } v; v.i = ((unsigned int)u) << 16; return v.f;
}
__device__ __forceinline__ unsigned short f2bf(float f) {
  union { float f; unsigned int u; } v; v.f = f;
  unsigned int r = v.u + 0x7fffu + ((v.u >> 16) & 1u);
  return (unsigned short)(r >> 16);
}
__device__ __forceinline__ float rcpf(float x) { return __builtin_amdgcn_rcpf(x); }
__device__ __forceinline__ u64 packft(float f, unsigned tag) {
  union { float f; unsigned u; } v; v.f = f;
  return ((u64)tag << 32) | (u64)v.u;
}
__device__ __forceinline__ float lo_f(u64 x) {
  union { unsigned u; float f; } v; v.u = (unsigned)x; return v.f;
}
__device__ __forceinline__ unsigned hi_u(u64 x) { return (unsigned)(x >> 32); }
__device__ __forceinline__ void postv(u64* p, u64 v) {
  __hip_atomic_store(p, v, __ATOMIC_RELAXED, __HIP_MEMORY_SCOPE_AGENT);
}
__device__ __forceinline__ u64 loadv(const u64* p) {
  return __hip_atomic_load(p, __ATOMIC_RELAXED, __HIP_MEMORY_SCOPE_AGENT);
}

// ============ single merged prep kernel ======================================
// ranges: [0,NB_WDEC) Wdb | [.,+NB_Z) WgT/WxS/zero/hallpad | [.,+1024) seqproj | [.,+256) xproj
#define NB_WDEC 4728   // NP2*KP/8/256
#define NB_Z    1611   // ceil((236544+28224+98304+49152)/256)
__global__ void k_prep(const float* __restrict__ Wih, const float* __restrict__ Whh,
                       const float* __restrict__ attWx, const float* __restrict__ Wd,
                       const float* __restrict__ ctx, const float* __restrict__ attWs,
                       const float* __restrict__ x, const float* __restrict__ bih,
                       const float* __restrict__ bhh,
                       unsigned short* __restrict__ Wdb, float* __restrict__ WgT,
                       unsigned short* __restrict__ WxS, u64* __restrict__ Abuf,
                       u64* __restrict__ Pbuf, unsigned short* __restrict__ ETs,
                       unsigned short* __restrict__ ctxb, float* __restrict__ Xp,
                       unsigned short* __restrict__ hall) {
  const int bid = blockIdx.x, tid = threadIdx.x;
  __shared__ float sbuf[2688];
  if (bid < NB_WDEC) {
    // Wdb[v][k] = bf16(Wd[v][k]) for v<VV,k<HH else 0 (8 elems/thread, no straddle)
    size_t e0 = ((size_t)bid * 256 + tid) * 8;
    int v = (int)(e0 / KP), k = (int)(e0 - (size_t)v * KP);
    unsigned short o[8];
    if (v < VV && k < HH) {
      const float* src = Wd + (size_t)v * HH + k;
      #pragma unroll
      for (int i = 0; i < 8; ++i) o[i] = f2bf(src[i]);
    } else {
      #pragma unroll
      for (int i = 0; i < 8; ++i) o[i] = 0;
    }
    *(uint4*)(Wdb + e0) = *(const uint4*)o;
    return;
  }
  int b2 = bid - NB_WDEC;
  if (b2 < NB_Z) {
    int idx = b2 * 256 + tid;
    const int T1 = NJ * KK * WKP;             // 236544
    const int T2 = T1 + NJ * RPB * HH;        // 264768
    const int ZH = BB * NJ * LSLOT;           // 49152 u64 each
    const int T3 = T2 + 2 * ZH;               // 363072
    const int T4 = T3 + BB * TT * (KP - HH);  // 412224
    if (idx < T1) {
      int j = idx / (KK * WKP); int r = idx - j * (KK * WKP);
      int k = r / WKP, col = r - k * WKP;
      float w = 0.f;
      if (col < CPB) {
        int gt = col / RPB, rr = col - gt * RPB;
        int gcol = gt * HH + j * RPB + rr;
        w = (k < HH) ? Wih[(size_t)gcol * IC + ID + k] : Whh[(size_t)gcol * HH + (k - HH)];
      }
      WgT[idx] = w;
    } else if (idx < T2) {
      int r = idx - T1;
      WxS[r] = f2bf(attWx[r]);
    } else if (idx < T3) {
      int r = idx - T2;
      if (r < ZH) Abuf[r] = 0ull;
      else        Pbuf[r - ZH] = 0ull;
    } else if (idx < T4) {
      int r = idx - T3;
      int bt = r / (KP - HH), c = r - bt * (KP - HH);
      hall[(size_t)bt * KP + HH + c] = 0;
    }
    return;
  }
  b2 -= NB_Z;
  if (b2 < 1024) {
    // seqproj: ETs[b][s][h] = bf16(exp(2P)), ctxb = bf16(ctx)
    const int b = b2 & 31;
    const int s0 = (b2 >> 5) * 16;
    for (int idx = tid; idx < 16 * HH; idx += 256) {
      float v = ctx[(size_t)(b * SS + s0) * HH + idx];
      sbuf[idx] = v;
      ctxb[(size_t)(b * SS + s0) * HH + idx] = f2bf(v);
    }
    __syncthreads();
    #pragma unroll
    for (int o = 0; o < 11; ++o) {
      int idx = o * 256 + tid;
      if (idx < 16 * HH) {
        int s = idx / HH, h = idx - s * HH;
        const float* cr = &sbuf[s * HH];
        float acc = 0.f;
        #pragma unroll 4
        for (int c = 0; c < HH; ++c) acc = fmaf(cr[c], attWs[c * HH + h], acc);
        ETs[(size_t)(b * SS + s0 + s) * HH + h] = f2bf(__expf(2.f * acc));
      }
    }
    return;
  }
  b2 -= 1024;
  {
    // xproj: Xp[b][t][i] = x@Wih_x^T + b_ih + b_hh (Wih rows read directly)
    const int t0 = (b2 & 7) * 8;
    const int b = b2 >> 3;
    for (int idx = tid; idx < 8 * ID; idx += 256)
      sbuf[idx] = x[(size_t)(b * TT + t0) * ID + idx];
    __syncthreads();
    for (int i = tid; i < G4; i += 256) {
      float bias = bih[i] + bhh[i];
      float acc[8];
      #pragma unroll
      for (int tt = 0; tt < 8; ++tt) acc[tt] = bias;
      const f32x4* wr = (const f32x4*)(Wih + (size_t)i * IC);  // row 16B-aligned
      for (int k4 = 0; k4 < ID / 4; ++k4) {
        f32x4 w = wr[k4];
        #pragma unroll
        for (int tt = 0; tt < 8; ++tt) {
          const float* xr = &sbuf[tt * ID + k4 * 4];
          acc[tt] += xr[0] * w[0] + xr[1] * w[1] + xr[2] * w[2] + xr[3] * w[3];
        }
      }
      #pragma unroll
      for (int tt = 0; tt < 8; ++tt)
        Xp[(size_t)(b * TT + t0 + tt) * G4 + i] = acc[tt];
    }
  }
}

// ============ recurrence: R6 exact structure (477us), tag sync ===============
__global__ __launch_bounds__(512, 1) void k_recur(
    const int* __restrict__ lens, const float* __restrict__ attb,
    const float* __restrict__ attv, const float* __restrict__ WgT,
    const unsigned short* __restrict__ WxS, const unsigned short* __restrict__ ETs,
    const unsigned short* __restrict__ ctxb, const float* __restrict__ Xp,
    u64* __restrict__ Abuf, u64* __restrict__ Pbuf,
    unsigned short* __restrict__ hall) {
  const int b = blockIdx.x & 31;
  const int j = blockIdx.x >> 5;
  const int tid = threadIdx.x;

  __shared__ float WgL[KK][WKP];            // 118272 B, [k][col]
  __shared__ unsigned short EL[SBLK][EPAD]; // 21760 B
  __shared__ unsigned short WxL[RPB][HH];   // 7056 B
  __shared__ float scratch[512];
  __shared__ float redH[504], redC[504];
  __shared__ float gE[HH], hsh[HH], abL[HH], vL[HH], attn[HH];
  __shared__ float esh[SBLK], hLoc[RPB], cLoc[RPB], wsum[8];
  __shared__ float sumv_s, bsum_s;

  {
    const f32x4* src = (const f32x4*)(WgT + (size_t)j * KK * WKP);
    f32x4* dst = (f32x4*)WgL;
    for (int i = tid; i < KK * WKP / 4; i += 512) dst[i] = src[i];
  }
  for (int i = tid; i < SBLK * HH; i += 512) {
    int s = i / HH, h = i - s * HH;
    EL[s][h] = ETs[((size_t)b * SS + j * SBLK + s) * HH + h];
  }
  for (int i = tid; i < RPB * HH; i += 512)
    ((unsigned short*)WxL)[i] = WxS[(size_t)j * RPB * HH + i];
  if (tid < HH) { abL[tid] = attb[tid]; vL[tid] = attv[tid]; }
  if (tid < RPB) cLoc[tid] = 0.f;
  __syncthreads();
  if (tid == 0) {
    float s = 0.f;
    for (int h = 0; h < HH; ++h) s += vL[h];
    sumv_s = s;
  }
  const int len = lens[b];
  const int sbase = j * SBLK;
  u64* Amine = Abuf + (size_t)(b * NJ + j) * LSLOT;
  u64* Pmine = Pbuf + (size_t)(b * NJ + j) * LSLOT;
  __syncthreads();

  for (int t = 0; t < TT; ++t) {
    // ---- Xp prefetch for this block's 21 rows (consumed late)
    float xpr0 = 0.f, xpr1 = 0.f, xpr2 = 0.f, xpr3 = 0.f;
    if (tid < RPB) {
      const float* xp = Xp + ((size_t)b * TT + t) * G4 + j * RPB + tid;
      xpr0 = xp[0]; xpr1 = xp[HH]; xpr2 = xp[2 * HH]; xpr3 = xp[3 * HH];
    }
    // ---- gE + hsh: poll tag-embedded a-partials (8) + h value (1)
    if (tid < HH) {
      float a = abL[tid], hv = 0.f;
      if (t > 0) {
        const unsigned want = (unsigned)t;
        const int jh = tid / RPB, hr = tid - jh * RPB;
        u64 va[9];
        int g = 0;
        for (;;) {
          #pragma unroll
          for (int jj = 0; jj < NJ; ++jj)
            va[jj] = loadv(&Abuf[(size_t)(b * NJ + jj) * LSLOT + tid]);
          va[8] = loadv(&Abuf[(size_t)(b * NJ + jh) * LSLOT + HH + hr]);
          bool ok = true;
          #pragma unroll
          for (int q = 0; q < 9; ++q) ok &= (hi_u(va[q]) >= want);
          if (ok) break;
          __builtin_amdgcn_s_sleep(1);
          if (++g > (1 << 24)) break;
        }
        #pragma unroll
        for (int jj = 0; jj < NJ; ++jj) a += lo_f(va[jj]);
        hv = lo_f(va[8]);
      }
      gE[tid] = __expf(2.f * a);
      hsh[tid] = hv;
    }
    __syncthreads();                                     // BAR A
    // ---- B + softmax (wave-local)
    {
      int w = tid >> 6, lane = tid & 63;
      int sl = w * 8 + (lane >> 3);
      int hg = lane & 7;
      const unsigned short* er = &EL[sl][hg * RPB];
      const int hb = hg * RPB;
      float ep = 0.f;
      #pragma unroll 7
      for (int i = 0; i < RPB; ++i)
        ep += vL[hb + i] * rcpf(fmaf(gE[hb + i], bf2f(er[i]), 1.f));
      ep += __shfl_xor(ep, 1); ep += __shfl_xor(ep, 2); ep += __shfl_xor(ep, 4);
      float eh = (sbase + sl < len) ? __expf(sumv_s - 2.f * ep) : 0.f;
      float ws = (hg == 0) ? eh : 0.f;
      ws += __shfl_xor(ws, 8); ws += __shfl_xor(ws, 16); ws += __shfl_xor(ws, 32);
      if (lane == 0) wsum[w] = ws;
      if (hg == 0) esh[sl] = eh;
    }
    __syncthreads();                                     // BAR B
    // ---- C partials + bsum
    if (tid < 504) {
      int c = tid % HH, ch = tid / HH;
      const unsigned short* cb = ctxb + ((size_t)b * SS + sbase) * HH + c;
      float p = 0.f;
      for (int s = ch; s < SBLK; s += 3)
        p = fmaf(esh[s], bf2f(cb[(size_t)s * HH]), p);
      scratch[ch * HH + c] = p;
    } else if (tid == 504) {
      float bs = 0.f;
      #pragma unroll
      for (int w = 0; w < 8; ++w) bs += wsum[w];
      bsum_s = bs;
    }
    __syncthreads();                                     // BAR C
    // ---- post P (tag-embedded)
    if (tid < HH) {
      float p = scratch[tid] + scratch[HH + tid] + scratch[2 * HH + tid];
      postv(&Pmine[tid], packft(p, (unsigned)(t + 1)));
    } else if (tid == HH) {
      postv(&Pmine[HH], packft(bsum_s, (unsigned)(t + 1)));
    }
    // ---- D_h (overlaps P propagation)
    if (tid < 504) {
      int col = tid % CPB, kc = tid / CPB;
      int k0 = HH + kc * 28;
      float acc = 0.f;
      #pragma unroll 7
      for (int i = 0; i < 28; ++i)
        acc = fmaf(WgL[k0 + i][col], hsh[kc * 28 + i], acc);
      redH[kc * CPB + col] = acc;
    }
    // ---- attn finalize: poll p-lines directly
    if (tid < HH) {
      const unsigned want = (unsigned)(t + 1);
      u64 pv[NJ], bv[NJ];
      int g = 0;
      for (;;) {
        #pragma unroll
        for (int jj = 0; jj < NJ; ++jj) {
          const u64* pb = Pbuf + (size_t)(b * NJ + jj) * LSLOT;
          pv[jj] = loadv(&pb[tid]);
          bv[jj] = loadv(&pb[HH]);
        }
        bool ok = true;
        #pragma unroll
        for (int jj = 0; jj < NJ; ++jj) ok &= (hi_u(pv[jj]) >= want) & (hi_u(bv[jj]) >= want);
        if (ok) break;
        __builtin_amdgcn_s_sleep(1);
        if (++g > (1 << 24)) break;
      }
      float s = 0.f, den = 0.f;
      #pragma unroll
      for (int jj = 0; jj < NJ; ++jj) { s += lo_f(pv[jj]); den += lo_f(bv[jj]); }
      attn[tid] = s * rcpf(den);
    }
    __syncthreads();                                     // BAR D
    // ---- D_c
    if (tid < 504) {
      int col = tid % CPB, kc = tid / CPB;
      int k0 = kc * 28;
      float acc = 0.f;
      #pragma unroll 7
      for (int i = 0; i < 28; ++i)
        acc = fmaf(WgL[k0 + i][col], attn[k0 + i], acc);
      redC[kc * CPB + col] = acc;
    }
    __syncthreads();                                     // BAR E
    // ---- gates + LSTM (21 threads), plain u16 hall store
    if (tid < RPB) {
      float g0 = xpr0, g1 = xpr1, g2 = xpr2, g3 = xpr3;
      #pragma unroll
      for (int kc = 0; kc < 6; ++kc) {
        const float* rh = &redH[kc * CPB];
        const float* rc = &redC[kc * CPB];
        g0 += rh[tid] + rc[tid];
        g1 += rh[RPB + tid] + rc[RPB + tid];
        g2 += rh[2 * RPB + tid] + rc[2 * RPB + tid];
        g3 += rh[3 * RPB + tid] + rc[3 * RPB + tid];
      }
      float si = rcpf(1.f + __expf(-g0));
      float sf = rcpf(1.f + __expf(-g1));
      float tg = 1.f - 2.f * rcpf(1.f + __expf(2.f * g2));
      float so = rcpf(1.f + __expf(-g3));
      float cn = fmaf(sf, cLoc[tid], si * tg);
      float tc = 1.f - 2.f * rcpf(1.f + __expf(2.f * cn));
      float hn = so * tc;
      cLoc[tid] = cn; hLoc[tid] = hn;
      hall[((size_t)b * TT + t) * KP + j * RPB + tid] = f2bf(hn);
    }
    __syncthreads();                                     // BAR F
    // ---- a_j = h_slice @ Wx_slice (504 threads, 7 FMA each)
    if (tid < 504) {
      int col = tid % HH, ch = tid / HH;
      float acc = 0.f;
      #pragma unroll
      for (int r = ch * 7; r < ch * 7 + 7; ++r)
        acc = fmaf(hLoc[r], bf2f(WxL[r][col]), acc);
      scratch[ch * HH + col] = acc;
    }
    __syncthreads();                                     // BAR G
    // ---- post a-partials + h values (tag-embedded)
    if (tid < HH) {
      float a = scratch[tid] + scratch[HH + tid] + scratch[2 * HH + tid];
      postv(&Amine[tid], packft(a, (unsigned)(t + 1)));
    } else if (tid < HH + RPB) {
      postv(&Amine[tid], packft(hLoc[tid - HH], (unsigned)(t + 1)));
    }
  }
}

// ============ decode GEMM: 256x256 tiles, 512 threads, plain epilogue ========
__global__ __launch_bounds__(512) void k_decode(const unsigned short* __restrict__ hallb,
                                                const unsigned short* __restrict__ wdb,
                                                float* __restrict__ out) {
  __shared__ __align__(16) unsigned short As[256 * LP];
  __shared__ __align__(16) unsigned short Bs[256 * LP];
  const int tid = threadIdx.x;
  const int n0 = blockIdx.x * 256, m0 = blockIdx.y * 256;
  const int lane = tid & 63, wid = tid >> 6;
  const int wm = wid >> 2, wn = wid & 3;
  const int lr = lane & 15, lk = lane >> 4;
  f32x4 acc[8][4];
  #pragma unroll
  for (int i = 0; i < 8; ++i)
    #pragma unroll
    for (int jj = 0; jj < 4; ++jj) acc[i][jj] = (f32x4)0.f;

  for (int k0 = 0; k0 < KP; k0 += 64) {
    if (k0) __syncthreads();
    #pragma unroll
    for (int i = 0; i < 4; ++i) {
      int flat = i * 512 + tid;
      int row = flat >> 3;
      int c8 = flat & 7;
      uint4 va = *(const uint4*)(hallb + (size_t)(m0 + row) * KP + k0 + c8 * 8);
      *(uint4*)&As[row * LP + c8 * 8] = va;
      uint4 vb = *(const uint4*)(wdb + (size_t)(n0 + row) * KP + k0 + c8 * 8);
      *(uint4*)&Bs[row * LP + c8 * 8] = vb;
    }
    __syncthreads();
    #pragma unroll
    for (int kk = 0; kk < 64; kk += 32) {
      bf16x8 af[8], bfr[4];
      #pragma unroll
      for (int mi = 0; mi < 8; ++mi)
        af[mi] = *(const bf16x8*)&As[(wm * 128 + mi * 16 + lr) * LP + kk + lk * 8];
      #pragma unroll
      for (int ni = 0; ni < 4; ++ni)
        bfr[ni] = *(const bf16x8*)&Bs[(wn * 64 + ni * 16 + lr) * LP + kk + lk * 8];
      #pragma unroll
      for (int mi = 0; mi < 8; ++mi)
        #pragma unroll
        for (int ni = 0; ni < 4; ++ni)
          acc[mi][ni] = __builtin_amdgcn_mfma_f32_16x16x32_bf16(
              af[mi], bfr[ni], acc[mi][ni], 0, 0, 0);
    }
  }
  #pragma unroll
  for (int mi = 0; mi < 8; ++mi)
    #pragma unroll
    for (int ni = 0; ni < 4; ++ni) {
      int col = n0 + wn * 64 + ni * 16 + lr;
      if (col < VV) {
        #pragma unroll
        for (int r = 0; r < 4; ++r) {
          int row = m0 + wm * 128 + mi * 16 + lk * 4 + r;
          out[(size_t)row * VV + col] = acc[mi][ni][r];
        }
      }
    }
}

extern "C" void kernel_launch(void* const* d_in, const int* in_sizes, int n_in,
                              void* d_out, int out_size, void* d_ws, size_t ws_size,
                              hipStream_t stream) {
  (void)in_sizes; (void)n_in; (void)out_size; (void)ws_size;
  const float* x     = (const float*)d_in[0];
  const float* ctx   = (const float*)d_in[1];
  const int*   lens  = (const int*)d_in[2];
  const float* Wih   = (const float*)d_in[3];
  const float* Whh   = (const float*)d_in[4];
  const float* bih   = (const float*)d_in[5];
  const float* bhh   = (const float*)d_in[6];
  const float* attWx = (const float*)d_in[7];
  const float* attWs = (const float*)d_in[8];
  const float* attb  = (const float*)d_in[9];
  const float* attv  = (const float*)d_in[10];
  const float* Wdec  = (const float*)d_in[11];
  float* out = (float*)d_out;

  char* base = (char*)d_ws;
  size_t off = 0;
  auto alloc = [&](size_t bytes) -> void* {
    off = (off + 255) & ~(size_t)255;
    void* p = base + off;
    off += bytes;
    return p;
  };
  unsigned short* ETs  = (unsigned short*)alloc((size_t)BB * SS * HH * 2);
  unsigned short* ctxb = (unsigned short*)alloc((size_t)BB * SS * HH * 2);
  float*          Xp   = (float*)alloc((size_t)BB * TT * G4 * 4);
  unsigned short* hall = (unsigned short*)alloc((size_t)BB * TT * KP * 2);
  unsigned short* Wdb  = (unsigned short*)alloc((size_t)NP2 * KP * 2);
  float*          WgT  = (float*)alloc((size_t)NJ * KK * WKP * 4);
  unsigned short* WxS  = (unsigned short*)alloc((size_t)NJ * RPB * HH * 2);
  u64*            Abuf = (u64*)alloc((size_t)BB * NJ * LSLOT * 8);
  u64*            Pbuf = (u64*)alloc((size_t)BB * NJ * LSLOT * 8);

  k_prep<<<dim3(NB_WDEC + NB_Z + 1024 + 256), dim3(256), 0, stream>>>(
      Wih, Whh, attWx, Wdec, ctx, attWs, x, bih, bhh,
      Wdb, WgT, WxS, Abuf, Pbuf, ETs, ctxb, Xp, hall);
  {
    const int* a0 = lens; const float* a1 = attb; const float* a2 = attv;
    const float* a3 = WgT; const unsigned short* a4 = WxS;
    const unsigned short* a5 = ETs; const unsigned short* a6 = ctxb;
    const float* a7 = Xp; u64* a8 = Abuf; u64* a9 = Pbuf;
    unsigned short* a10 = hall;
    void* args[] = { &a0, &a1, &a2, &a3, &a4, &a5, &a6, &a7, &a8, &a9, &a10 };
    hipLaunchCooperativeKernel((void*)k_recur, dim3(BB * NJ), dim3(512), args, 0, stream);
  }
  k_decode<<<dim3(NTN, 8), dim3(512), 0, stream>>>(hall, Wdb, out);
}

// Round 14
// 755.485 us; speedup vs baseline: 1.7573x; 1.0690x over previous
//
#include <hip/hip_runtime.h>
#include <stdint.h>

#define BB 32
#define TT 64
#define ID 300
#define HH 168
#define SS 512
#define VV 50257
#define G4 672     // 4*H
#define IC 468     // I + C
#define KP 192     // K padded for decode MFMA
#define NP2 50432  // V padded to 256 (197 tiles)
#define NJ 8       // blocks per batch
#define RPB 21     // h rows per block
#define CPB 84     // gate cols per block
#define KK 336     // gate K dim
#define WKP 88     // WgT col pad
#define EPAD 170   // ETs LDS row pad (85 dwords, gcd(85,32)=1)
#define SBLK 64    // s positions per block
#define LSLOT 192  // u64 slots per (b,j) bucket
#define LP 72      // decode LDS row pad in shorts
#define NTN 197    // decode n-tiles (50432/256)

typedef float f32x4 __attribute__((ext_vector_type(4)));
typedef short bf16x8 __attribute__((ext_vector_type(8)));
typedef unsigned long long u64;

__device__ __forceinline__ float bf2f(unsigned short u) {
  union { unsigned int i; float f; } v; v.i = ((unsigned int)u) << 16; return v.f;
}
__device__ __forceinline__ unsigned short f2bf(float f) {
  union { float f; unsigned int u; } v; v.f = f;
  unsigned int r = v.u + 0x7fffu + ((v.u >> 16) & 1u);
  return (unsigned short)(r >> 16);
}
__device__ __forceinline__ float rcpf(float x) { return __builtin_amdgcn_rcpf(x); }
__device__ __forceinline__ u64 packft(float f, unsigned tag) {
  union { float f; unsigned u; } v; v.f = f;
  return ((u64)tag << 32) | (u64)v.u;
}
__device__ __forceinline__ float lo_f(u64 x) {
  union { unsigned u; float f; } v; v.u = (unsigned)x; return v.f;
}
__device__ __forceinline__ unsigned hi_u(u64 x) { return (unsigned)(x >> 32); }
__device__ __forceinline__ void postv(u64* p, u64 v) {
  __hip_atomic_store(p, v, __ATOMIC_RELAXED, __HIP_MEMORY_SCOPE_AGENT);
}
__device__ __forceinline__ u64 loadv(const u64* p) {
  return __hip_atomic_load(p, __ATOMIC_RELAXED, __HIP_MEMORY_SCOPE_AGENT);
}

// ============ prep1: Wdb bf16 LINEAR | WihxT | WgT fp32 | WxS | zero | pad ===
#define NB_WDEC 4728   // NP2*KP/8/256
#define NB_TR   788    // ceil(ID*G4/256)
#define NB_Z    1611   // ceil(412224/256)
__global__ void k_prep(const float* __restrict__ Wih, const float* __restrict__ Whh,
                       const float* __restrict__ attWx, const float* __restrict__ Wd,
                       float* __restrict__ WihxT, unsigned short* __restrict__ Wdb,
                       float* __restrict__ WgT, unsigned short* __restrict__ WxS,
                       u64* __restrict__ Abuf, u64* __restrict__ Pbuf,
                       unsigned short* __restrict__ hall) {
  const int bid = blockIdx.x, tid = threadIdx.x;
  if (bid < NB_WDEC) {
    // Wdb[v][k] = bf16(Wd[v][k]) for v<VV,k<HH else 0 — LINEAR, matches hall layout
    size_t e0 = ((size_t)bid * 256 + tid) * 8;
    int v = (int)(e0 / KP), k = (int)(e0 - (size_t)v * KP);
    unsigned short o[8];
    if (v < VV && k < HH) {
      const float* src = Wd + (size_t)v * HH + k;
      #pragma unroll
      for (int i = 0; i < 8; ++i) o[i] = f2bf(src[i]);
    } else {
      #pragma unroll
      for (int i = 0; i < 8; ++i) o[i] = 0;
    }
    *(uint4*)(Wdb + e0) = *(const uint4*)o;
    return;
  }
  if (bid < NB_WDEC + NB_TR) {
    int idx = (bid - NB_WDEC) * 256 + tid;
    if (idx < ID * G4) {
      int k = idx / G4, i = idx - k * G4;
      WihxT[idx] = Wih[(size_t)i * IC + k];
    }
    return;
  }
  int idx = (bid - NB_WDEC - NB_TR) * 256 + tid;
  const int T1 = NJ * KK * WKP;             // 236544
  const int T2 = T1 + NJ * RPB * HH;        // 264768
  const int ZH = BB * NJ * LSLOT;           // 49152 u64 each
  const int T3 = T2 + 2 * ZH;               // 363072
  const int T4 = T3 + BB * TT * (KP - HH);  // 412224
  if (idx < T1) {
    int j = idx / (KK * WKP); int r = idx - j * (KK * WKP);
    int k = r / WKP, col = r - k * WKP;
    float w = 0.f;
    if (col < CPB) {
      int gt = col / RPB, rr = col - gt * RPB;
      int gcol = gt * HH + j * RPB + rr;
      w = (k < HH) ? Wih[(size_t)gcol * IC + ID + k] : Whh[(size_t)gcol * HH + (k - HH)];
    }
    WgT[idx] = w;
  } else if (idx < T2) {
    int r = idx - T1;
    WxS[r] = f2bf(attWx[r]);
  } else if (idx < T3) {
    int r = idx - T2;
    if (r < ZH) Abuf[r] = 0ull;
    else        Pbuf[r - ZH] = 0ull;
  } else if (idx < T4) {
    int r = idx - T3;
    int bt = r / (KP - HH), c = r - bt * (KP - HH);
    hall[(size_t)bt * KP + HH + c] = 0;
  }
}

// ============ prep2: seqproj (linear ETs) + xproj (coalesced WihxT) ==========
__global__ void k_seqxp(const float* __restrict__ ctx, const float* __restrict__ Ws,
                        const float* __restrict__ x, const float* __restrict__ WihxT,
                        const float* __restrict__ bih, const float* __restrict__ bhh,
                        unsigned short* __restrict__ ETs, unsigned short* __restrict__ ctxb,
                        float* __restrict__ Xp) {
  __shared__ float sbuf[2688];
  const int tid = threadIdx.x;
  if (blockIdx.x < 1024) {
    const int b = blockIdx.x & 31;
    const int s0 = (blockIdx.x >> 5) * 16;
    for (int idx = tid; idx < 16 * HH; idx += 256) {
      float v = ctx[(size_t)(b * SS + s0) * HH + idx];
      sbuf[idx] = v;
      ctxb[(size_t)(b * SS + s0) * HH + idx] = f2bf(v);
    }
    __syncthreads();
    #pragma unroll
    for (int o = 0; o < 11; ++o) {
      int idx = o * 256 + tid;
      if (idx < 16 * HH) {
        int s = idx / HH, h = idx - s * HH;
        const float* cr = &sbuf[s * HH];
        float acc = 0.f;
        #pragma unroll 4
        for (int c = 0; c < HH; ++c) acc = fmaf(cr[c], Ws[c * HH + h], acc);
        ETs[(size_t)(b * SS + s0 + s) * HH + h] = f2bf(__expf(2.f * acc));
      }
    }
  } else {
    const int r = blockIdx.x - 1024;
    const int t0 = (r & 7) * 8;
    const int b = r >> 3;
    for (int idx = tid; idx < 8 * ID; idx += 256)
      sbuf[idx] = x[(size_t)(b * TT + t0) * ID + idx];
    __syncthreads();
    for (int i = tid; i < G4; i += 256) {
      float bias = bih[i] + bhh[i];
      float acc[8];
      #pragma unroll
      for (int tt = 0; tt < 8; ++tt) acc[tt] = bias;
      for (int k = 0; k < ID; ++k) {
        float w = WihxT[k * G4 + i];
        #pragma unroll
        for (int tt = 0; tt < 8; ++tt) acc[tt] += sbuf[tt * ID + k] * w;
      }
      #pragma unroll
      for (int tt = 0; tt < 8; ++tt)
        Xp[(size_t)(b * TT + t0 + tt) * G4 + i] = acc[tt];
    }
  }
}

// ============ recurrence: R11 exact structure (477us), tag sync ==============
__global__ __launch_bounds__(512, 1) void k_recur(
    const int* __restrict__ lens, const float* __restrict__ attb,
    const float* __restrict__ attv, const float* __restrict__ WgT,
    const unsigned short* __restrict__ WxS, const unsigned short* __restrict__ ETs,
    const unsigned short* __restrict__ ctxb, const float* __restrict__ Xp,
    u64* __restrict__ Abuf, u64* __restrict__ Pbuf,
    unsigned short* __restrict__ hall) {
  const int b = blockIdx.x & 31;
  const int j = blockIdx.x >> 5;
  const int tid = threadIdx.x;

  __shared__ float WgL[KK][WKP];            // 118272 B, [k][col]
  __shared__ unsigned short EL[SBLK][EPAD]; // 21760 B
  __shared__ unsigned short WxL[RPB][HH];   // 7056 B
  __shared__ float scratch[512];
  __shared__ float redH[504], redC[504];
  __shared__ float gE[HH], hsh[HH], abL[HH], vL[HH], attn[HH];
  __shared__ float esh[SBLK], hLoc[RPB], cLoc[RPB], wsum[8];
  __shared__ float sumv_s, bsum_s;

  {
    const f32x4* src = (const f32x4*)(WgT + (size_t)j * KK * WKP);
    f32x4* dst = (f32x4*)WgL;
    for (int i = tid; i < KK * WKP / 4; i += 512) dst[i] = src[i];
  }
  for (int i = tid; i < SBLK * HH; i += 512) {
    int s = i / HH, h = i - s * HH;
    EL[s][h] = ETs[((size_t)b * SS + j * SBLK + s) * HH + h];
  }
  for (int i = tid; i < RPB * HH; i += 512)
    ((unsigned short*)WxL)[i] = WxS[(size_t)j * RPB * HH + i];
  if (tid < HH) { abL[tid] = attb[tid]; vL[tid] = attv[tid]; }
  if (tid < RPB) cLoc[tid] = 0.f;
  __syncthreads();
  if (tid == 0) {
    float s = 0.f;
    for (int h = 0; h < HH; ++h) s += vL[h];
    sumv_s = s;
  }
  const int len = lens[b];
  const int sbase = j * SBLK;
  u64* Amine = Abuf + (size_t)(b * NJ + j) * LSLOT;
  u64* Pmine = Pbuf + (size_t)(b * NJ + j) * LSLOT;
  __syncthreads();

  for (int t = 0; t < TT; ++t) {
    // ---- Xp prefetch for this block's 21 rows (consumed late)
    float xpr0 = 0.f, xpr1 = 0.f, xpr2 = 0.f, xpr3 = 0.f;
    if (tid < RPB) {
      const float* xp = Xp + ((size_t)b * TT + t) * G4 + j * RPB + tid;
      xpr0 = xp[0]; xpr1 = xp[HH]; xpr2 = xp[2 * HH]; xpr3 = xp[3 * HH];
    }
    // ---- gE + hsh: poll tag-embedded a-partials (8) + h value (1)
    if (tid < HH) {
      float a = abL[tid], hv = 0.f;
      if (t > 0) {
        const unsigned want = (unsigned)t;
        const int jh = tid / RPB, hr = tid - jh * RPB;
        u64 va[9];
        int g = 0;
        for (;;) {
          #pragma unroll
          for (int jj = 0; jj < NJ; ++jj)
            va[jj] = loadv(&Abuf[(size_t)(b * NJ + jj) * LSLOT + tid]);
          va[8] = loadv(&Abuf[(size_t)(b * NJ + jh) * LSLOT + HH + hr]);
          bool ok = true;
          #pragma unroll
          for (int q = 0; q < 9; ++q) ok &= (hi_u(va[q]) >= want);
          if (ok) break;
          __builtin_amdgcn_s_sleep(1);
          if (++g > (1 << 24)) break;
        }
        #pragma unroll
        for (int jj = 0; jj < NJ; ++jj) a += lo_f(va[jj]);
        hv = lo_f(va[8]);
      }
      gE[tid] = __expf(2.f * a);
      hsh[tid] = hv;
    }
    __syncthreads();                                     // BAR A
    // ---- B + softmax (wave-local)
    {
      int w = tid >> 6, lane = tid & 63;
      int sl = w * 8 + (lane >> 3);
      int hg = lane & 7;
      const unsigned short* er = &EL[sl][hg * RPB];
      const int hb = hg * RPB;
      float ep = 0.f;
      #pragma unroll 7
      for (int i = 0; i < RPB; ++i)
        ep += vL[hb + i] * rcpf(fmaf(gE[hb + i], bf2f(er[i]), 1.f));
      ep += __shfl_xor(ep, 1); ep += __shfl_xor(ep, 2); ep += __shfl_xor(ep, 4);
      float eh = (sbase + sl < len) ? __expf(sumv_s - 2.f * ep) : 0.f;
      float ws = (hg == 0) ? eh : 0.f;
      ws += __shfl_xor(ws, 8); ws += __shfl_xor(ws, 16); ws += __shfl_xor(ws, 32);
      if (lane == 0) wsum[w] = ws;
      if (hg == 0) esh[sl] = eh;
    }
    __syncthreads();                                     // BAR B
    // ---- C partials + bsum
    if (tid < 504) {
      int c = tid % HH, ch = tid / HH;
      const unsigned short* cb = ctxb + ((size_t)b * SS + sbase) * HH + c;
      float p = 0.f;
      for (int s = ch; s < SBLK; s += 3)
        p = fmaf(esh[s], bf2f(cb[(size_t)s * HH]), p);
      scratch[ch * HH + c] = p;
    } else if (tid == 504) {
      float bs = 0.f;
      #pragma unroll
      for (int w = 0; w < 8; ++w) bs += wsum[w];
      bsum_s = bs;
    }
    __syncthreads();                                     // BAR C
    // ---- post P (tag-embedded)
    if (tid < HH) {
      float p = scratch[tid] + scratch[HH + tid] + scratch[2 * HH + tid];
      postv(&Pmine[tid], packft(p, (unsigned)(t + 1)));
    } else if (tid == HH) {
      postv(&Pmine[HH], packft(bsum_s, (unsigned)(t + 1)));
    }
    // ---- D_h (overlaps P propagation)
    if (tid < 504) {
      int col = tid % CPB, kc = tid / CPB;
      int k0 = HH + kc * 28;
      float acc = 0.f;
      #pragma unroll 7
      for (int i = 0; i < 28; ++i)
        acc = fmaf(WgL[k0 + i][col], hsh[kc * 28 + i], acc);
      redH[kc * CPB + col] = acc;
    }
    // ---- attn finalize: poll p-lines directly
    if (tid < HH) {
      const unsigned want = (unsigned)(t + 1);
      u64 pv[NJ], bv[NJ];
      int g = 0;
      for (;;) {
        #pragma unroll
        for (int jj = 0; jj < NJ; ++jj) {
          const u64* pb = Pbuf + (size_t)(b * NJ + jj) * LSLOT;
          pv[jj] = loadv(&pb[tid]);
          bv[jj] = loadv(&pb[HH]);
        }
        bool ok = true;
        #pragma unroll
        for (int jj = 0; jj < NJ; ++jj) ok &= (hi_u(pv[jj]) >= want) & (hi_u(bv[jj]) >= want);
        if (ok) break;
        __builtin_amdgcn_s_sleep(1);
        if (++g > (1 << 24)) break;
      }
      float s = 0.f, den = 0.f;
      #pragma unroll
      for (int jj = 0; jj < NJ; ++jj) { s += lo_f(pv[jj]); den += lo_f(bv[jj]); }
      attn[tid] = s * rcpf(den);
    }
    __syncthreads();                                     // BAR D
    // ---- D_c
    if (tid < 504) {
      int col = tid % CPB, kc = tid / CPB;
      int k0 = kc * 28;
      float acc = 0.f;
      #pragma unroll 7
      for (int i = 0; i < 28; ++i)
        acc = fmaf(WgL[k0 + i][col], attn[k0 + i], acc);
      redC[kc * CPB + col] = acc;
    }
    __syncthreads();                                     // BAR E
    // ---- gates + LSTM (21 threads), plain u16 hall store
    if (tid < RPB) {
      float g0 = xpr0, g1 = xpr1, g2 = xpr2, g3 = xpr3;
      #pragma unroll
      for (int kc = 0; kc < 6; ++kc) {
        const float* rh = &redH[kc * CPB];
        const float* rc = &redC[kc * CPB];
        g0 += rh[tid] + rc[tid];
        g1 += rh[RPB + tid] + rc[RPB + tid];
        g2 += rh[2 * RPB + tid] + rc[2 * RPB + tid];
        g3 += rh[3 * RPB + tid] + rc[3 * RPB + tid];
      }
      float si = rcpf(1.f + __expf(-g0));
      float sf = rcpf(1.f + __expf(-g1));
      float tg = 1.f - 2.f * rcpf(1.f + __expf(2.f * g2));
      float so = rcpf(1.f + __expf(-g3));
      float cn = fmaf(sf, cLoc[tid], si * tg);
      float tc = 1.f - 2.f * rcpf(1.f + __expf(2.f * cn));
      float hn = so * tc;
      cLoc[tid] = cn; hLoc[tid] = hn;
      hall[((size_t)b * TT + t) * KP + j * RPB + tid] = f2bf(hn);
    }
    __syncthreads();                                     // BAR F
    // ---- a_j = h_slice @ Wx_slice (504 threads, 7 FMA each)
    if (tid < 504) {
      int col = tid % HH, ch = tid / HH;
      float acc = 0.f;
      #pragma unroll
      for (int r = ch * 7; r < ch * 7 + 7; ++r)
        acc = fmaf(hLoc[r], bf2f(WxL[r][col]), acc);
      scratch[ch * HH + col] = acc;
    }
    __syncthreads();                                     // BAR G
    // ---- post a-partials + h values (tag-embedded)
    if (tid < HH) {
      float a = scratch[tid] + scratch[HH + tid] + scratch[2 * HH + tid];
      postv(&Amine[tid], packft(a, (unsigned)(t + 1)));
    } else if (tid < HH + RPB) {
      postv(&Amine[tid], packft(hLoc[tid - HH], (unsigned)(t + 1)));
    }
  }
}

// ============ decode GEMM: 256x256 tiles, 512 threads, plain epilogue ========
__global__ __launch_bounds__(512) void k_decode(const unsigned short* __restrict__ hallb,
                                                const unsigned short* __restrict__ wdb,
                                                float* __restrict__ out) {
  __shared__ __align__(16) unsigned short As[256 * LP];
  __shared__ __align__(16) unsigned short Bs[256 * LP];
  const int tid = threadIdx.x;
  const int n0 = blockIdx.x * 256, m0 = blockIdx.y * 256;
  const int lane = tid & 63, wid = tid >> 6;
  const int wm = wid >> 2, wn = wid & 3;
  const int lr = lane & 15, lk = lane >> 4;
  f32x4 acc[8][4];
  #pragma unroll
  for (int i = 0; i < 8; ++i)
    #pragma unroll
    for (int jj = 0; jj < 4; ++jj) acc[i][jj] = (f32x4)0.f;

  for (int k0 = 0; k0 < KP; k0 += 64) {
    if (k0) __syncthreads();
    #pragma unroll
    for (int i = 0; i < 4; ++i) {
      int flat = i * 512 + tid;
      int row = flat >> 3;
      int c8 = flat & 7;
      uint4 va = *(const uint4*)(hallb + (size_t)(m0 + row) * KP + k0 + c8 * 8);
      *(uint4*)&As[row * LP + c8 * 8] = va;
      uint4 vb = *(const uint4*)(wdb + (size_t)(n0 + row) * KP + k0 + c8 * 8);
      *(uint4*)&Bs[row * LP + c8 * 8] = vb;
    }
    __syncthreads();
    #pragma unroll
    for (int kk = 0; kk < 64; kk += 32) {
      bf16x8 af[8], bfr[4];
      #pragma unroll
      for (int mi = 0; mi < 8; ++mi)
        af[mi] = *(const bf16x8*)&As[(wm * 128 + mi * 16 + lr) * LP + kk + lk * 8];
      #pragma unroll
      for (int ni = 0; ni < 4; ++ni)
        bfr[ni] = *(const bf16x8*)&Bs[(wn * 64 + ni * 16 + lr) * LP + kk + lk * 8];
      #pragma unroll
      for (int mi = 0; mi < 8; ++mi)
        #pragma unroll
        for (int ni = 0; ni < 4; ++ni)
          acc[mi][ni] = __builtin_amdgcn_mfma_f32_16x16x32_bf16(
              af[mi], bfr[ni], acc[mi][ni], 0, 0, 0);
    }
  }
  #pragma unroll
  for (int mi = 0; mi < 8; ++mi)
    #pragma unroll
    for (int ni = 0; ni < 4; ++ni) {
      int col = n0 + wn * 64 + ni * 16 + lr;
      if (col < VV) {
        #pragma unroll
        for (int r = 0; r < 4; ++r) {
          int row = m0 + wm * 128 + mi * 16 + lk * 4 + r;
          out[(size_t)row * VV + col] = acc[mi][ni][r];
        }
      }
    }
}

extern "C" void kernel_launch(void* const* d_in, const int* in_sizes, int n_in,
                              void* d_out, int out_size, void* d_ws, size_t ws_size,
                              hipStream_t stream) {
  (void)in_sizes; (void)n_in; (void)out_size; (void)ws_size;
  const float* x     = (const float*)d_in[0];
  const float* ctx   = (const float*)d_in[1];
  const int*   lens  = (const int*)d_in[2];
  const float* Wih   = (const float*)d_in[3];
  const float* Whh   = (const float*)d_in[4];
  const float* bih   = (const float*)d_in[5];
  const float* bhh   = (const float*)d_in[6];
  const float* attWx = (const float*)d_in[7];
  const float* attWs = (const float*)d_in[8];
  const float* attb  = (const float*)d_in[9];
  const float* attv  = (const float*)d_in[10];
  const float* Wdec  = (const float*)d_in[11];
  float* out = (float*)d_out;

  char* base = (char*)d_ws;
  size_t off = 0;
  auto alloc = [&](size_t bytes) -> void* {
    off = (off + 255) & ~(size_t)255;
    void* p = base + off;
    off += bytes;
    return p;
  };
  unsigned short* ETs  = (unsigned short*)alloc((size_t)BB * SS * HH * 2);
  unsigned short* ctxb = (unsigned short*)alloc((size_t)BB * SS * HH * 2);
  float*          Xp   = (float*)alloc((size_t)BB * TT * G4 * 4);
  float*          WihxT= (float*)alloc((size_t)ID * G4 * 4);
  unsigned short* hall = (unsigned short*)alloc((size_t)BB * TT * KP * 2);
  unsigned short* Wdb  = (unsigned short*)alloc((size_t)NP2 * KP * 2);
  float*          WgT  = (float*)alloc((size_t)NJ * KK * WKP * 4);
  unsigned short* WxS  = (unsigned short*)alloc((size_t)NJ * RPB * HH * 2);
  u64*            Abuf = (u64*)alloc((size_t)BB * NJ * LSLOT * 8);
  u64*            Pbuf = (u64*)alloc((size_t)BB * NJ * LSLOT * 8);

  k_prep<<<dim3(NB_WDEC + NB_TR + NB_Z), dim3(256), 0, stream>>>(
      Wih, Whh, attWx, Wdec, WihxT, Wdb, WgT, WxS, Abuf, Pbuf, hall);
  k_seqxp<<<dim3(1024 + 256), dim3(256), 0, stream>>>(ctx, attWs, x, WihxT,
                                                      bih, bhh, ETs, ctxb, Xp);
  {
    const int* a0 = lens; const float* a1 = attb; const float* a2 = attv;
    const float* a3 = WgT; const unsigned short* a4 = WxS;
    const unsigned short* a5 = ETs; const unsigned short* a6 = ctxb;
    const float* a7 = Xp; u64* a8 = Abuf; u64* a9 = Pbuf;
    unsigned short* a10 = hall;
    void* args[] = { &a0, &a1, &a2, &a3, &a4, &a5, &a6, &a7, &a8, &a9, &a10 };
    hipLaunchCooperativeKernel((void*)k_recur, dim3(BB * NJ), dim3(512), args, 0, stream);
  }
  k_decode<<<dim3(NTN, (BB * TT) / 256), dim3(512), 0, stream>>>(hall, Wdb, out);
}

// Round 15
// 737.127 us; speedup vs baseline: 1.8011x; 1.0249x over previous
//
#include <hip/hip_runtime.h>
#include <stdint.h>

#define BB 32
#define TT 64
#define ID 300
#define HH 168
#define SS 512
#define VV 50257
#define G4 672     // 4*H
#define IC 468     // I + C
#define KP 192     // K padded for decode MFMA
#define NP2 50432  // V padded to 256 (197 tiles)
#define NJ 8       // blocks per batch
#define RPB 21     // h rows per block
#define CPB 84     // gate cols per block
#define KK 336     // gate K dim
#define WKP 88     // WgT col pad
#define EPAD 170   // ETs LDS row pad (85 dwords, gcd(85,32)=1)
#define SBLK 64    // s positions per block
#define LSLOT 192  // u64 slots per (b,j) bucket
#define LP 72      // decode LDS row pad in shorts
#define NTN 197    // decode n-tiles (50432/256)

typedef float f32x4 __attribute__((ext_vector_type(4)));
typedef short bf16x8 __attribute__((ext_vector_type(8)));
typedef unsigned long long u64;

__device__ __forceinline__ float bf2f(unsigned short u) {
  union { unsigned int i; float f; } v; v.i = ((unsigned int)u) << 16; return v.f;
}
__device__ __forceinline__ unsigned short f2bf(float f) {
  union { float f; unsigned int u; } v; v.f = f;
  unsigned int r = v.u + 0x7fffu + ((v.u >> 16) & 1u);
  return (unsigned short)(r >> 16);
}
__device__ __forceinline__ float rcpf(float x) { return __builtin_amdgcn_rcpf(x); }
__device__ __forceinline__ u64 packft(float f, unsigned tag) {
  union { float f; unsigned u; } v; v.f = f;
  return ((u64)tag << 32) | (u64)v.u;
}
__device__ __forceinline__ float lo_f(u64 x) {
  union { unsigned u; float f; } v; v.u = (unsigned)x; return v.f;
}
__device__ __forceinline__ unsigned hi_u(u64 x) { return (unsigned)(x >> 32); }
__device__ __forceinline__ void postv(u64* p, u64 v) {
  __hip_atomic_store(p, v, __ATOMIC_RELAXED, __HIP_MEMORY_SCOPE_AGENT);
}
__device__ __forceinline__ u64 loadv(const u64* p) {
  return __hip_atomic_load(p, __ATOMIC_RELAXED, __HIP_MEMORY_SCOPE_AGENT);
}

// ============ prep1: Wdb bf16 LINEAR | WihxT | WgT fp32 | WxS | zero | pad ===
#define NB_WDEC 4728   // NP2*KP/8/256
#define NB_TR   788    // ceil(ID*G4/256)
#define NB_Z    1611   // ceil(412224/256)
__global__ void k_prep(const float* __restrict__ Wih, const float* __restrict__ Whh,
                       const float* __restrict__ attWx, const float* __restrict__ Wd,
                       float* __restrict__ WihxT, unsigned short* __restrict__ Wdb,
                       float* __restrict__ WgT, unsigned short* __restrict__ WxS,
                       u64* __restrict__ Abuf, u64* __restrict__ Pbuf,
                       unsigned short* __restrict__ hall) {
  const int bid = blockIdx.x, tid = threadIdx.x;
  if (bid < NB_WDEC) {
    // Wdb[v][k] = bf16(Wd[v][k]) for v<VV,k<HH else 0 — LINEAR, matches hall layout
    size_t e0 = ((size_t)bid * 256 + tid) * 8;
    int v = (int)(e0 / KP), k = (int)(e0 - (size_t)v * KP);
    unsigned short o[8];
    if (v < VV && k < HH) {
      const float* src = Wd + (size_t)v * HH + k;
      #pragma unroll
      for (int i = 0; i < 8; ++i) o[i] = f2bf(src[i]);
    } else {
      #pragma unroll
      for (int i = 0; i < 8; ++i) o[i] = 0;
    }
    *(uint4*)(Wdb + e0) = *(const uint4*)o;
    return;
  }
  if (bid < NB_WDEC + NB_TR) {
    int idx = (bid - NB_WDEC) * 256 + tid;
    if (idx < ID * G4) {
      int k = idx / G4, i = idx - k * G4;
      WihxT[idx] = Wih[(size_t)i * IC + k];
    }
    return;
  }
  int idx = (bid - NB_WDEC - NB_TR) * 256 + tid;
  const int T1 = NJ * KK * WKP;             // 236544
  const int T2 = T1 + NJ * RPB * HH;        // 264768
  const int ZH = BB * NJ * LSLOT;           // 49152 u64 each
  const int T3 = T2 + 2 * ZH;               // 363072
  const int T4 = T3 + BB * TT * (KP - HH);  // 412224
  if (idx < T1) {
    int j = idx / (KK * WKP); int r = idx - j * (KK * WKP);
    int k = r / WKP, col = r - k * WKP;
    float w = 0.f;
    if (col < CPB) {
      int gt = col / RPB, rr = col - gt * RPB;
      int gcol = gt * HH + j * RPB + rr;
      w = (k < HH) ? Wih[(size_t)gcol * IC + ID + k] : Whh[(size_t)gcol * HH + (k - HH)];
    }
    WgT[idx] = w;
  } else if (idx < T2) {
    int r = idx - T1;
    WxS[r] = f2bf(attWx[r]);
  } else if (idx < T3) {
    int r = idx - T2;
    if (r < ZH) Abuf[r] = 0ull;
    else        Pbuf[r - ZH] = 0ull;
  } else if (idx < T4) {
    int r = idx - T3;
    int bt = r / (KP - HH), c = r - bt * (KP - HH);
    hall[(size_t)bt * KP + HH + c] = 0;
  }
}

// ============ prep2: seqproj (linear ETs) + xproj (coalesced WihxT) ==========
__global__ void k_seqxp(const float* __restrict__ ctx, const float* __restrict__ Ws,
                        const float* __restrict__ x, const float* __restrict__ WihxT,
                        const float* __restrict__ bih, const float* __restrict__ bhh,
                        unsigned short* __restrict__ ETs, unsigned short* __restrict__ ctxb,
                        float* __restrict__ Xp) {
  __shared__ float sbuf[2688];
  const int tid = threadIdx.x;
  if (blockIdx.x < 1024) {
    const int b = blockIdx.x & 31;
    const int s0 = (blockIdx.x >> 5) * 16;
    for (int idx = tid; idx < 16 * HH; idx += 256) {
      float v = ctx[(size_t)(b * SS + s0) * HH + idx];
      sbuf[idx] = v;
      ctxb[(size_t)(b * SS + s0) * HH + idx] = f2bf(v);
    }
    __syncthreads();
    #pragma unroll
    for (int o = 0; o < 11; ++o) {
      int idx = o * 256 + tid;
      if (idx < 16 * HH) {
        int s = idx / HH, h = idx - s * HH;
        const float* cr = &sbuf[s * HH];
        float acc = 0.f;
        #pragma unroll 4
        for (int c = 0; c < HH; ++c) acc = fmaf(cr[c], Ws[c * HH + h], acc);
        ETs[(size_t)(b * SS + s0 + s) * HH + h] = f2bf(__expf(2.f * acc));
      }
    }
  } else {
    const int r = blockIdx.x - 1024;
    const int t0 = (r & 7) * 8;
    const int b = r >> 3;
    for (int idx = tid; idx < 8 * ID; idx += 256)
      sbuf[idx] = x[(size_t)(b * TT + t0) * ID + idx];
    __syncthreads();
    for (int i = tid; i < G4; i += 256) {
      float bias = bih[i] + bhh[i];
      float acc[8];
      #pragma unroll
      for (int tt = 0; tt < 8; ++tt) acc[tt] = bias;
      for (int k = 0; k < ID; ++k) {
        float w = WihxT[k * G4 + i];
        #pragma unroll
        for (int tt = 0; tt < 8; ++tt) acc[tt] += sbuf[tt * ID + k] * w;
      }
      #pragma unroll
      for (int tt = 0; tt < 8; ++tt)
        Xp[(size_t)(b * TT + t0 + tt) * G4 + i] = acc[tt];
    }
  }
}

// ============ recurrence: R14 structure, REGULAR launch (256 blocks = 256 CUs,
// 157KB LDS forces 1 block/CU -> all co-resident by capacity; persistent-kernel
// pattern; poll guards bound any pathology to a wrong answer, not a hang) =====
__global__ __launch_bounds__(512, 1) void k_recur(
    const int* __restrict__ lens, const float* __restrict__ attb,
    const float* __restrict__ attv, const float* __restrict__ WgT,
    const unsigned short* __restrict__ WxS, const unsigned short* __restrict__ ETs,
    const unsigned short* __restrict__ ctxb, const float* __restrict__ Xp,
    u64* __restrict__ Abuf, u64* __restrict__ Pbuf,
    unsigned short* __restrict__ hall) {
  const int b = blockIdx.x & 31;
  const int j = blockIdx.x >> 5;
  const int tid = threadIdx.x;

  __shared__ float WgL[KK][WKP];            // 118272 B, [k][col]
  __shared__ unsigned short EL[SBLK][EPAD]; // 21760 B
  __shared__ unsigned short WxL[RPB][HH];   // 7056 B
  __shared__ float scratch[512];
  __shared__ float redH[504], redC[504];
  __shared__ float gE[HH], hsh[HH], abL[HH], vL[HH], attn[HH];
  __shared__ float esh[SBLK], hLoc[RPB], cLoc[RPB], wsum[8];
  __shared__ float sumv_s, bsum_s;

  {
    const f32x4* src = (const f32x4*)(WgT + (size_t)j * KK * WKP);
    f32x4* dst = (f32x4*)WgL;
    for (int i = tid; i < KK * WKP / 4; i += 512) dst[i] = src[i];
  }
  for (int i = tid; i < SBLK * HH; i += 512) {
    int s = i / HH, h = i - s * HH;
    EL[s][h] = ETs[((size_t)b * SS + j * SBLK + s) * HH + h];
  }
  for (int i = tid; i < RPB * HH; i += 512)
    ((unsigned short*)WxL)[i] = WxS[(size_t)j * RPB * HH + i];
  if (tid < HH) { abL[tid] = attb[tid]; vL[tid] = attv[tid]; }
  if (tid < RPB) cLoc[tid] = 0.f;
  __syncthreads();
  if (tid == 0) {
    float s = 0.f;
    for (int h = 0; h < HH; ++h) s += vL[h];
    sumv_s = s;
  }
  const int len = lens[b];
  const int sbase = j * SBLK;
  u64* Amine = Abuf + (size_t)(b * NJ + j) * LSLOT;
  u64* Pmine = Pbuf + (size_t)(b * NJ + j) * LSLOT;
  __syncthreads();

  for (int t = 0; t < TT; ++t) {
    // ---- Xp prefetch for this block's 21 rows (consumed late)
    float xpr0 = 0.f, xpr1 = 0.f, xpr2 = 0.f, xpr3 = 0.f;
    if (tid < RPB) {
      const float* xp = Xp + ((size_t)b * TT + t) * G4 + j * RPB + tid;
      xpr0 = xp[0]; xpr1 = xp[HH]; xpr2 = xp[2 * HH]; xpr3 = xp[3 * HH];
    }
    // ---- gE + hsh: poll tag-embedded a-partials (8) + h value (1)
    if (tid < HH) {
      float a = abL[tid], hv = 0.f;
      if (t > 0) {
        const unsigned want = (unsigned)t;
        const int jh = tid / RPB, hr = tid - jh * RPB;
        u64 va[9];
        int g = 0;
        for (;;) {
          #pragma unroll
          for (int jj = 0; jj < NJ; ++jj)
            va[jj] = loadv(&Abuf[(size_t)(b * NJ + jj) * LSLOT + tid]);
          va[8] = loadv(&Abuf[(size_t)(b * NJ + jh) * LSLOT + HH + hr]);
          bool ok = true;
          #pragma unroll
          for (int q = 0; q < 9; ++q) ok &= (hi_u(va[q]) >= want);
          if (ok) break;
          __builtin_amdgcn_s_sleep(1);
          if (++g > (1 << 24)) break;
        }
        #pragma unroll
        for (int jj = 0; jj < NJ; ++jj) a += lo_f(va[jj]);
        hv = lo_f(va[8]);
      }
      gE[tid] = __expf(2.f * a);
      hsh[tid] = hv;
    }
    __syncthreads();                                     // BAR A
    // ---- B + softmax (wave-local)
    {
      int w = tid >> 6, lane = tid & 63;
      int sl = w * 8 + (lane >> 3);
      int hg = lane & 7;
      const unsigned short* er = &EL[sl][hg * RPB];
      const int hb = hg * RPB;
      float ep = 0.f;
      #pragma unroll 7
      for (int i = 0; i < RPB; ++i)
        ep += vL[hb + i] * rcpf(fmaf(gE[hb + i], bf2f(er[i]), 1.f));
      ep += __shfl_xor(ep, 1); ep += __shfl_xor(ep, 2); ep += __shfl_xor(ep, 4);
      float eh = (sbase + sl < len) ? __expf(sumv_s - 2.f * ep) : 0.f;
      float ws = (hg == 0) ? eh : 0.f;
      ws += __shfl_xor(ws, 8); ws += __shfl_xor(ws, 16); ws += __shfl_xor(ws, 32);
      if (lane == 0) wsum[w] = ws;
      if (hg == 0) esh[sl] = eh;
    }
    __syncthreads();                                     // BAR B
    // ---- C partials + bsum
    if (tid < 504) {
      int c = tid % HH, ch = tid / HH;
      const unsigned short* cb = ctxb + ((size_t)b * SS + sbase) * HH + c;
      float p = 0.f;
      for (int s = ch; s < SBLK; s += 3)
        p = fmaf(esh[s], bf2f(cb[(size_t)s * HH]), p);
      scratch[ch * HH + c] = p;
    } else if (tid == 504) {
      float bs = 0.f;
      #pragma unroll
      for (int w = 0; w < 8; ++w) bs += wsum[w];
      bsum_s = bs;
    }
    __syncthreads();                                     // BAR C
    // ---- post P (tag-embedded)
    if (tid < HH) {
      float p = scratch[tid] + scratch[HH + tid] + scratch[2 * HH + tid];
      postv(&Pmine[tid], packft(p, (unsigned)(t + 1)));
    } else if (tid == HH) {
      postv(&Pmine[HH], packft(bsum_s, (unsigned)(t + 1)));
    }
    // ---- D_h (overlaps P propagation)
    if (tid < 504) {
      int col = tid % CPB, kc = tid / CPB;
      int k0 = HH + kc * 28;
      float acc = 0.f;
      #pragma unroll 7
      for (int i = 0; i < 28; ++i)
        acc = fmaf(WgL[k0 + i][col], hsh[kc * 28 + i], acc);
      redH[kc * CPB + col] = acc;
    }
    // ---- attn finalize: poll p-lines directly
    if (tid < HH) {
      const unsigned want = (unsigned)(t + 1);
      u64 pv[NJ], bv[NJ];
      int g = 0;
      for (;;) {
        #pragma unroll
        for (int jj = 0; jj < NJ; ++jj) {
          const u64* pb = Pbuf + (size_t)(b * NJ + jj) * LSLOT;
          pv[jj] = loadv(&pb[tid]);
          bv[jj] = loadv(&pb[HH]);
        }
        bool ok = true;
        #pragma unroll
        for (int jj = 0; jj < NJ; ++jj) ok &= (hi_u(pv[jj]) >= want) & (hi_u(bv[jj]) >= want);
        if (ok) break;
        __builtin_amdgcn_s_sleep(1);
        if (++g > (1 << 24)) break;
      }
      float s = 0.f, den = 0.f;
      #pragma unroll
      for (int jj = 0; jj < NJ; ++jj) { s += lo_f(pv[jj]); den += lo_f(bv[jj]); }
      attn[tid] = s * rcpf(den);
    }
    __syncthreads();                                     // BAR D
    // ---- D_c
    if (tid < 504) {
      int col = tid % CPB, kc = tid / CPB;
      int k0 = kc * 28;
      float acc = 0.f;
      #pragma unroll 7
      for (int i = 0; i < 28; ++i)
        acc = fmaf(WgL[k0 + i][col], attn[k0 + i], acc);
      redC[kc * CPB + col] = acc;
    }
    __syncthreads();                                     // BAR E
    // ---- gates + LSTM (21 threads), plain u16 hall store
    if (tid < RPB) {
      float g0 = xpr0, g1 = xpr1, g2 = xpr2, g3 = xpr3;
      #pragma unroll
      for (int kc = 0; kc < 6; ++kc) {
        const float* rh = &redH[kc * CPB];
        const float* rc = &redC[kc * CPB];
        g0 += rh[tid] + rc[tid];
        g1 += rh[RPB + tid] + rc[RPB + tid];
        g2 += rh[2 * RPB + tid] + rc[2 * RPB + tid];
        g3 += rh[3 * RPB + tid] + rc[3 * RPB + tid];
      }
      float si = rcpf(1.f + __expf(-g0));
      float sf = rcpf(1.f + __expf(-g1));
      float tg = 1.f - 2.f * rcpf(1.f + __expf(2.f * g2));
      float so = rcpf(1.f + __expf(-g3));
      float cn = fmaf(sf, cLoc[tid], si * tg);
      float tc = 1.f - 2.f * rcpf(1.f + __expf(2.f * cn));
      float hn = so * tc;
      cLoc[tid] = cn; hLoc[tid] = hn;
      hall[((size_t)b * TT + t) * KP + j * RPB + tid] = f2bf(hn);
    }
    __syncthreads();                                     // BAR F
    // ---- a_j = h_slice @ Wx_slice (504 threads, 7 FMA each)
    if (tid < 504) {
      int col = tid % HH, ch = tid / HH;
      float acc = 0.f;
      #pragma unroll
      for (int r = ch * 7; r < ch * 7 + 7; ++r)
        acc = fmaf(hLoc[r], bf2f(WxL[r][col]), acc);
      scratch[ch * HH + col] = acc;
    }
    __syncthreads();                                     // BAR G
    // ---- post a-partials + h values (tag-embedded)
    if (tid < HH) {
      float a = scratch[tid] + scratch[HH + tid] + scratch[2 * HH + tid];
      postv(&Amine[tid], packft(a, (unsigned)(t + 1)));
    } else if (tid < HH + RPB) {
      postv(&Amine[tid], packft(hLoc[tid - HH], (unsigned)(t + 1)));
    }
  }
}

// ============ decode GEMM: 256x256 tiles, 512 threads, plain epilogue ========
__global__ __launch_bounds__(512) void k_decode(const unsigned short* __restrict__ hallb,
                                                const unsigned short* __restrict__ wdb,
                                                float* __restrict__ out) {
  __shared__ __align__(16) unsigned short As[256 * LP];
  __shared__ __align__(16) unsigned short Bs[256 * LP];
  const int tid = threadIdx.x;
  const int n0 = blockIdx.x * 256, m0 = blockIdx.y * 256;
  const int lane = tid & 63, wid = tid >> 6;
  const int wm = wid >> 2, wn = wid & 3;
  const int lr = lane & 15, lk = lane >> 4;
  f32x4 acc[8][4];
  #pragma unroll
  for (int i = 0; i < 8; ++i)
    #pragma unroll
    for (int jj = 0; jj < 4; ++jj) acc[i][jj] = (f32x4)0.f;

  for (int k0 = 0; k0 < KP; k0 += 64) {
    if (k0) __syncthreads();
    #pragma unroll
    for (int i = 0; i < 4; ++i) {
      int flat = i * 512 + tid;
      int row = flat >> 3;
      int c8 = flat & 7;
      uint4 va = *(const uint4*)(hallb + (size_t)(m0 + row) * KP + k0 + c8 * 8);
      *(uint4*)&As[row * LP + c8 * 8] = va;
      uint4 vb = *(const uint4*)(wdb + (size_t)(n0 + row) * KP + k0 + c8 * 8);
      *(uint4*)&Bs[row * LP + c8 * 8] = vb;
    }
    __syncthreads();
    #pragma unroll
    for (int kk = 0; kk < 64; kk += 32) {
      bf16x8 af[8], bfr[4];
      #pragma unroll
      for (int mi = 0; mi < 8; ++mi)
        af[mi] = *(const bf16x8*)&As[(wm * 128 + mi * 16 + lr) * LP + kk + lk * 8];
      #pragma unroll
      for (int ni = 0; ni < 4; ++ni)
        bfr[ni] = *(const bf16x8*)&Bs[(wn * 64 + ni * 16 + lr) * LP + kk + lk * 8];
      #pragma unroll
      for (int mi = 0; mi < 8; ++mi)
        #pragma unroll
        for (int ni = 0; ni < 4; ++ni)
          acc[mi][ni] = __builtin_amdgcn_mfma_f32_16x16x32_bf16(
              af[mi], bfr[ni], acc[mi][ni], 0, 0, 0);
    }
  }
  #pragma unroll
  for (int mi = 0; mi < 8; ++mi)
    #pragma unroll
    for (int ni = 0; ni < 4; ++ni) {
      int col = n0 + wn * 64 + ni * 16 + lr;
      if (col < VV) {
        #pragma unroll
        for (int r = 0; r < 4; ++r) {
          int row = m0 + wm * 128 + mi * 16 + lk * 4 + r;
          out[(size_t)row * VV + col] = acc[mi][ni][r];
        }
      }
    }
}

extern "C" void kernel_launch(void* const* d_in, const int* in_sizes, int n_in,
                              void* d_out, int out_size, void* d_ws, size_t ws_size,
                              hipStream_t stream) {
  (void)in_sizes; (void)n_in; (void)out_size; (void)ws_size;
  const float* x     = (const float*)d_in[0];
  const float* ctx   = (const float*)d_in[1];
  const int*   lens  = (const int*)d_in[2];
  const float* Wih   = (const float*)d_in[3];
  const float* Whh   = (const float*)d_in[4];
  const float* bih   = (const float*)d_in[5];
  const float* bhh   = (const float*)d_in[6];
  const float* attWx = (const float*)d_in[7];
  const float* attWs = (const float*)d_in[8];
  const float* attb  = (const float*)d_in[9];
  const float* attv  = (const float*)d_in[10];
  const float* Wdec  = (const float*)d_in[11];
  float* out = (float*)d_out;

  char* base = (char*)d_ws;
  size_t off = 0;
  auto alloc = [&](size_t bytes) -> void* {
    off = (off + 255) & ~(size_t)255;
    void* p = base + off;
    off += bytes;
    return p;
  };
  unsigned short* ETs  = (unsigned short*)alloc((size_t)BB * SS * HH * 2);
  unsigned short* ctxb = (unsigned short*)alloc((size_t)BB * SS * HH * 2);
  float*          Xp   = (float*)alloc((size_t)BB * TT * G4 * 4);
  float*          WihxT= (float*)alloc((size_t)ID * G4 * 4);
  unsigned short* hall = (unsigned short*)alloc((size_t)BB * TT * KP * 2);
  unsigned short* Wdb  = (unsigned short*)alloc((size_t)NP2 * KP * 2);
  float*          WgT  = (float*)alloc((size_t)NJ * KK * WKP * 4);
  unsigned short* WxS  = (unsigned short*)alloc((size_t)NJ * RPB * HH * 2);
  u64*            Abuf = (u64*)alloc((size_t)BB * NJ * LSLOT * 8);
  u64*            Pbuf = (u64*)alloc((size_t)BB * NJ * LSLOT * 8);

  k_prep<<<dim3(NB_WDEC + NB_TR + NB_Z), dim3(256), 0, stream>>>(
      Wih, Whh, attWx, Wdec, WihxT, Wdb, WgT, WxS, Abuf, Pbuf, hall);
  k_seqxp<<<dim3(1024 + 256), dim3(256), 0, stream>>>(ctx, attWs, x, WihxT,
                                                      bih, bhh, ETs, ctxb, Xp);
  // regular (non-cooperative) launch: 256 blocks, 157KB LDS -> 1 block/CU,
  // grid == CU count -> all blocks co-resident by capacity arithmetic
  k_recur<<<dim3(BB * NJ), dim3(512), 0, stream>>>(lens, attb, attv, WgT, WxS,
                                                   ETs, ctxb, Xp, Abuf, Pbuf, hall);
  k_decode<<<dim3(NTN, (BB * TT) / 256), dim3(512), 0, stream>>>(hall, Wdb, out);
}